// Round 3
// baseline (2186.557 us; speedup 1.0000x reference)
//
#include <hip/hip_runtime.h>
#include <hip/hip_bf16.h>

#define BS 8
#define D 512
#define CCH 128
#define LMAP 8
#define NLAYERS 9

// ---- module-global scratch (no d_ws dependence, no hipMalloc) ----
__device__ float g_bufA[(size_t)BS * CCH * 4096];   // 16.78 MB
__device__ float g_bufB[(size_t)BS * CCH * 4096];   // 16.78 MB
__device__ float g_w[2][BS * D];
__device__ float g_style[BS * CCH];
__device__ float g_rstd[BS * CCH];

__device__ __forceinline__ float leaky(float v) { return v >= 0.f ? v : 0.2f * v; }

// ---------------- PixelNorm: g_w[0][b,k] = z * rsqrt(mean(z^2) + 1e-8) ----------------
__global__ void pixelnorm_kernel(const float* __restrict__ z)
{
    int b = blockIdx.x, lane = threadIdx.x;   // 64 lanes
    float v[8];
    float ss = 0.f;
#pragma unroll
    for (int u = 0; u < 8; ++u) { v[u] = z[b * D + u * 64 + lane]; ss += v[u] * v[u]; }
#pragma unroll
    for (int off = 32; off > 0; off >>= 1) ss += __shfl_xor(ss, off, 64);
    float r = rsqrtf(ss * (1.f / 512.f) + 1e-8f);
#pragma unroll
    for (int u = 0; u < 8; ++u) g_w[0][b * D + u * 64 + lane] = v[u] * r;
}

// ---------------- Mapping FC: g_w[s^1] = leaky(g_w[s] @ W + b) ----------------
// grid (8 j-chunks of 64, BS), block 256 = 64 j x 4 k-parts
__global__ __launch_bounds__(256) void map_fc_kernel(
    int srcSel, const float* __restrict__ W, const float* __restrict__ bias)
{
    const float* win = g_w[srcSel];
    float* wout = g_w[srcSel ^ 1];
    int b = blockIdx.y;
    int jb = blockIdx.x * 64;
    int tid = threadIdx.x;
    int jl = tid & 63, kp = tid >> 6;
    __shared__ float xin[D];
    __shared__ float part[4][64];
    for (int k = tid; k < D; k += 256) xin[k] = win[b * D + k];
    __syncthreads();
    float acc = 0.f;
    const float* Wp = W + jb + jl;
    for (int k = kp * 128; k < kp * 128 + 128; ++k) acc += xin[k] * Wp[(size_t)k * D];
    part[kp][jl] = acc;
    __syncthreads();
    if (tid < 64) {
        float s = part[0][tid] + part[1][tid] + part[2][tid] + part[3][tid] + bias[jb + tid];
        wout[b * D + jb + tid] = leaky(s);
    }
}

// ---------------- style[b,c] = w@A_w + A_b ; rstd[b,co] = rsqrt(sum((W*style)^2)+1e-8) ------
// grid (8 cout-groups of 16, BS), block 256. Reads g_w[0] (final mapping output).
__global__ __launch_bounds__(256) void style_rstd_kernel(
    const float* __restrict__ Aw, const float* __restrict__ Ab,
    const float* __restrict__ convw)
{
    int b = blockIdx.y;
    int tid = threadIdx.x;
    __shared__ float st[CCH];
    __shared__ float part[256];
    {
        int c = tid & 127, half = tid >> 7;
        float a = 0.f;
        const float* wp = g_w[0] + b * D;
        for (int k = half * 256; k < half * 256 + 256; ++k) a += wp[k] * Aw[k * CCH + c];
        part[tid] = a;
    }
    __syncthreads();
    if (tid < CCH) {
        float s = part[tid] + part[tid + 128] + Ab[tid];
        st[tid] = s;
        if (blockIdx.x == 0) g_style[b * CCH + tid] = s;
    }
    __syncthreads();
    int col = tid >> 4;       // 0..15  (16 consecutive threads share one cout)
    int kpart = tid & 15;
    int cout = blockIdx.x * 16 + col;
    float s = 0.f;
    const float* wp = convw + ((size_t)cout * CCH + kpart * 8) * 9;
#pragma unroll
    for (int ci = 0; ci < 8; ++ci) {
        float sv = st[kpart * 8 + ci];
#pragma unroll
        for (int k = 0; k < 9; ++k) { float m = wp[ci * 9 + k] * sv; s += m * m; }
    }
#pragma unroll
    for (int off = 8; off > 0; off >>= 1) s += __shfl_down(s, off, 16);
    if (kpart == 0) g_rstd[b * CCH + cout] = rsqrtf(s + 1e-8f);
}

// ---------------- layer 0: x==0 so conv==0 -> out = leaky(noise*B_w + B_b), 4x4 ----------------
__global__ void layer0_kernel(const float* __restrict__ noise,
                              const float* __restrict__ Bw, const float* __restrict__ Bb)
{
    // total BS*CCH*16 = 16384 elements
    int idx = blockIdx.x * 256 + threadIdx.x;
    if (idx >= BS * CCH * 16) return;
    int pix = idx & 15;
    int c = (idx >> 4) & 127;
    int b = idx >> 11;
    float v = noise[b * 4096 + pix] * Bw[c] + Bb[c];
    g_bufA[((size_t)b * CCH + c) * 16 + pix] = leaky(v);
}

// ---------------- bilinear 2x upsample (jax half-pixel + boundary renorm) ----------------
__global__ void upsample_kernel(int srcSel, int Hin, int Win)
{
    const float* in = srcSel ? g_bufB : g_bufA;
    float* out = srcSel ? g_bufA : g_bufB;
    int Ho = Hin * 2, Wo = Win * 2;
    int total = BS * CCH * Ho * Wo;
    int idx = blockIdx.x * 256 + threadIdx.x;
    if (idx >= total) return;
    int x = idx % Wo;
    int y = (idx / Wo) % Ho;
    int bc = idx / (Wo * Ho);
    int my = y >> 1, mx = x >> 1;
    int y0, y1, x0, x1;
    float wy0, wy1, wx0, wx1;
    if ((y & 1) == 0) { y0 = my - 1; y1 = my; wy0 = 0.25f; wy1 = 0.75f; if (y0 < 0) { y0 = 0; wy0 = 0.f; wy1 = 1.f; } }
    else              { y0 = my; y1 = my + 1; wy0 = 0.75f; wy1 = 0.25f; if (y1 >= Hin) { y1 = Hin - 1; wy0 = 1.f; wy1 = 0.f; } }
    if ((x & 1) == 0) { x0 = mx - 1; x1 = mx; wx0 = 0.25f; wx1 = 0.75f; if (x0 < 0) { x0 = 0; wx0 = 0.f; wx1 = 1.f; } }
    else              { x0 = mx; x1 = mx + 1; wx0 = 0.75f; wx1 = 0.25f; if (x1 >= Win) { x1 = Win - 1; wx0 = 1.f; wx1 = 0.f; } }
    const float* p = in + (size_t)bc * Hin * Win;
    float v = wy0 * (wx0 * p[y0 * Win + x0] + wx1 * p[y0 * Win + x1])
            + wy1 * (wx0 * p[y1 * Win + x0] + wx1 * p[y1 * Win + x1]);
    out[idx] = v;
}

// ---------------- modulated 3x3 conv + noise + leaky ----------------
// Block tile: 64 pixels x 64 couts; thread: 4 px x 4 cout; cin chunked by 8 through LDS.
// out = leaky( rstd[b,co] * conv(x*style, W) + noise*B_w[co] + B_b[co] )
__global__ __launch_bounds__(256) void conv_mod_kernel(
    int srcSel, const float* __restrict__ convw,
    const float* __restrict__ noise,   // [BS][4096] layer slice
    const float* __restrict__ Bw, const float* __restrict__ Bb,
    int H, int W)
{
    const float* xin = srcSel ? g_bufB : g_bufA;
    float* xout = srcSel ? g_bufA : g_bufB;

    const int b = blockIdx.z;
    const int coBase = blockIdx.y * 64;
    const int pixBase = blockIdx.x * 64;
    const int tid = threadIdx.x;
    const int ns = H * W;
    const int R = 64 / W;          // rows per 64-px tile (W in {8..64}, pow2)
    const int haloR = R + 2;
    const int sW = W + 4;          // +2 halo, +2 pad so float4 reads stay in-bounds
    const int rowBase = pixBase / W;

    __shared__ __align__(16) float xs[8][204];       // max haloR*sW = 3*68 = 204
    __shared__ __align__(16) float wls[8][64][12];   // 9 used, padded to 12 for float4
    __shared__ float style_s[CCH];
    __shared__ float rstd_s[64], bw_s[64], bb_s[64];

    if (tid < CCH) style_s[tid] = g_style[b * CCH + tid];
    if (tid < 64) {
        int cout = coBase + tid;
        rstd_s[tid] = g_rstd[b * CCH + cout];
        bw_s[tid] = Bw[cout];
        bb_s[tid] = Bb[cout];
    }

    const int pgrp = tid & 15, cgrp = tid >> 4;
    const int pxl = pgrp * 4;          // local pixel base (4-aligned, never crosses a row)
    const int ry = pxl / W;
    const int rx = pxl % W;

    float acc[4][4] = {};

    const int xsCount = 8 * haloR * sW;
    const size_t base_in = (size_t)b * CCH * ns;

    for (int chunk = 0; chunk < 16; ++chunk) {
        const int cinBase = chunk * 8;
        __syncthreads();
        // stage style-modulated x tile (f32, zero-padded halo)
        for (int idx = tid; idx < xsCount; idx += 256) {
            int ci = idx / (haloR * sW);
            int rem = idx - ci * (haloR * sW);
            int r = rem / sW;
            int cx = rem - r * sW;
            int gy = rowBase - 1 + r;
            int gx = cx - 1;
            float v = 0.f;
            if (gy >= 0 && gy < H && gx >= 0 && gx < W)
                v = xin[base_in + (size_t)(cinBase + ci) * ns + gy * W + gx] * style_s[cinBase + ci];
            xs[ci][rem] = v;
        }
        // stage raw weights
        for (int idx = tid; idx < 8 * 64 * 9; idx += 256) {
            int co = idx / 72;
            int rem = idx - co * 72;
            int ci = rem / 9;
            int k = rem - ci * 9;
            wls[ci][co][k] = convw[(((size_t)coBase + co) * CCH + cinBase + ci) * 9 + k];
        }
        __syncthreads();

#pragma unroll
        for (int ci = 0; ci < 8; ++ci) {
            float xr[3][8];
#pragma unroll
            for (int dy = 0; dy < 3; ++dy) {
                const float4 a  = *reinterpret_cast<const float4*>(&xs[ci][(ry + dy) * sW + rx]);
                const float4 b4 = *reinterpret_cast<const float4*>(&xs[ci][(ry + dy) * sW + rx + 4]);
                xr[dy][0] = a.x;  xr[dy][1] = a.y;  xr[dy][2] = a.z;  xr[dy][3] = a.w;
                xr[dy][4] = b4.x; xr[dy][5] = b4.y; xr[dy][6] = b4.z; xr[dy][7] = b4.w;
            }
#pragma unroll
            for (int co = 0; co < 4; ++co) {
                const float4 w0 = *reinterpret_cast<const float4*>(&wls[ci][cgrp * 4 + co][0]);
                const float4 w1 = *reinterpret_cast<const float4*>(&wls[ci][cgrp * 4 + co][4]);
                const float  w8 = wls[ci][cgrp * 4 + co][8];
                const float wk[9] = {w0.x, w0.y, w0.z, w0.w, w1.x, w1.y, w1.z, w1.w, w8};
#pragma unroll
                for (int dy = 0; dy < 3; ++dy)
#pragma unroll
                    for (int dx = 0; dx < 3; ++dx)
#pragma unroll
                        for (int p = 0; p < 4; ++p)
                            acc[co][p] = fmaf(wk[dy * 3 + dx], xr[dy][dx + p], acc[co][p]);
            }
        }
    }

#pragma unroll
    for (int p = 0; p < 4; ++p) {
        int pix = pixBase + pxl + p;
        if (pix < ns) {
            float nz = noise[b * 4096 + pix];
#pragma unroll
            for (int co = 0; co < 4; ++co) {
                int col = cgrp * 4 + co;
                float v = acc[co][p] * rstd_s[col] + nz * bw_s[col] + bb_s[col];
                xout[base_in + (size_t)(coBase + col) * ns + pix] = leaky(v);
            }
        }
    }
}

// ---------------- toRGB: 3x3 conv C=128 -> 3, + bias, f32 out ----------------
__global__ __launch_bounds__(256) void rgb_kernel(int srcSel,
    const float* __restrict__ rgbw, const float* __restrict__ rgbb, float* __restrict__ out)
{
    const float* xin = srcSel ? g_bufB : g_bufA;
    int b = blockIdx.z, co = blockIdx.y;
    int px = blockIdx.x * 256 + threadIdx.x;   // 0..4095
    __shared__ float wr[CCH * 9];
    for (int idx = threadIdx.x; idx < CCH * 9; idx += 256)
        wr[idx] = rgbw[co * CCH * 9 + idx];
    __syncthreads();
    int y = px >> 6, x = px & 63;
    float acc = rgbb[co];
    const float* xp = xin + (size_t)b * CCH * 4096;
    for (int ci = 0; ci < CCH; ++ci) {
        const float* row = xp + ci * 4096;
#pragma unroll
        for (int ky = 0; ky < 3; ++ky) {
            int gy = y + ky - 1;
            if (gy < 0 || gy > 63) continue;
#pragma unroll
            for (int kx = 0; kx < 3; ++kx) {
                int gx = x + kx - 1;
                if (gx < 0 || gx > 63) continue;
                acc += wr[ci * 9 + ky * 3 + kx] * row[gy * 64 + gx];
            }
        }
    }
    out[((size_t)b * 3 + co) * 4096 + px] = acc;
}

// ---------------- launch ----------------
extern "C" void kernel_launch(void* const* d_in, const int* in_sizes, int n_in,
                              void* d_out, int out_size, void* d_ws, size_t ws_size,
                              hipStream_t stream)
{
    const float* latent = (const float*)d_in[0];
    const float* noise  = (const float*)d_in[1];
    const float* map_w  = (const float*)d_in[2];
    const float* map_b  = (const float*)d_in[3];
    const float* A_w    = (const float*)d_in[4];
    const float* A_b    = (const float*)d_in[5];
    const float* B_w    = (const float*)d_in[6];
    const float* B_b    = (const float*)d_in[7];
    const float* conv_w = (const float*)d_in[8];
    const float* rgb_w  = (const float*)d_in[9];
    const float* rgb_b  = (const float*)d_in[10];
    float* out = (float*)d_out;
    (void)d_ws; (void)ws_size;

    // ---- mapping ----
    pixelnorm_kernel<<<BS, 64, 0, stream>>>(latent);
    int wsel = 0;
    for (int i = 0; i < LMAP; ++i) {
        map_fc_kernel<<<dim3(8, BS), 256, 0, stream>>>(wsel, map_w + (size_t)i * D * D, map_b + i * D);
        wsel ^= 1;   // ends at 0 after 8 layers -> final w in g_w[0]
    }

    // ---- layer 0 (x == 0): out = leaky(noise*Bw + Bb) -> g_bufA ----
    layer0_kernel<<<(BS * CCH * 16 + 255) / 256, 256, 0, stream>>>(noise, B_w, B_b);

    int cur = 0;   // 0 => data in g_bufA, 1 => g_bufB
    int Hc = 4;
    for (int i = 1; i < NLAYERS; ++i) {
        if (i & 1) {
            int total = BS * CCH * Hc * 2 * Hc * 2;
            upsample_kernel<<<(total + 255) / 256, 256, 0, stream>>>(cur, Hc, Hc);
            Hc *= 2;
            cur ^= 1;
        }
        style_rstd_kernel<<<dim3(8, BS), 256, 0, stream>>>(
            A_w + (size_t)i * D * CCH, A_b + i * CCH,
            conv_w + (size_t)i * CCH * CCH * 9);
        int ns = Hc * Hc;
        conv_mod_kernel<<<dim3((ns + 63) / 64, 2, BS), 256, 0, stream>>>(
            cur, conv_w + (size_t)i * CCH * CCH * 9,
            noise + (size_t)i * BS * 4096, B_w + i * CCH, B_b + i * CCH, Hc, Hc);
        cur ^= 1;
    }

    rgb_kernel<<<dim3(16, 3, BS), 256, 0, stream>>>(cur, rgb_w, rgb_b, out);
}

// Round 4
// 786.578 us; speedup vs baseline: 2.7798x; 2.7798x over previous
//
#include <hip/hip_runtime.h>
#include <hip/hip_bf16.h>

#define BS 8
#define D 512
#define CCH 128
#define LMAP 8
#define NLAYERS 9

typedef short short8 __attribute__((ext_vector_type(8)));
typedef float f32x4 __attribute__((ext_vector_type(4)));

// ---- module-global scratch ----
__device__ float g_bufA[(size_t)BS * CCH * 4096];   // 16.78 MB
__device__ float g_bufB[(size_t)BS * CCH * 4096];   // 16.78 MB
__device__ float g_w[2][BS * D];
__device__ float g_style[BS * CCH];
__device__ float g_rstd[BS * CCH];
// packed bf16 weight fragments: [layer][tap][chunk4][cogrp8][lane64][8]
__device__ short g_wpack[(size_t)NLAYERS * 9 * 4 * 8 * 64 * 8];   // 2.65 MB
// rgb: [tap][chunk4][lane64][8] (M=16 rows, rows 0-2 real)
__device__ short g_rgbpack[9 * 4 * 64 * 8];

__device__ __forceinline__ float leaky(float v) { return v >= 0.f ? v : 0.2f * v; }
__device__ __forceinline__ short f2b(float f) {
    __hip_bfloat16 h = __float2bfloat16(f);
    return *reinterpret_cast<short*>(&h);
}

// ---------------- weight fragment prep (all 9 layers) ----------------
__global__ __launch_bounds__(256) void wprep_kernel(const float* __restrict__ convw)
{
    int idx = blockIdx.x * 256 + threadIdx.x;        // [layer][tap][chunk][cogrp][lane]
    if (idx >= NLAYERS * 9 * 4 * 8 * 64) return;
    int lane = idx & 63;
    int cogrp = (idx >> 6) & 7;
    int chunk = (idx >> 9) & 3;
    int t = idx >> 11;           // layer*9 + tap
    int layer = t / 9, tap = t - layer * 9;
    int co = cogrp * 16 + (lane & 15);
    int ci0 = chunk * 32 + (lane >> 4) * 8;
    short8 v;
#pragma unroll
    for (int j = 0; j < 8; ++j)
        v[j] = f2b(convw[(((size_t)layer * CCH + co) * CCH + ci0 + j) * 9 + tap]);
    *reinterpret_cast<short8*>(&g_wpack[(size_t)idx * 8]) = v;
}

__global__ void rgbprep_kernel(const float* __restrict__ rgbw)
{
    int idx = blockIdx.x * 256 + threadIdx.x;        // [tap][chunk][lane]
    if (idx >= 9 * 4 * 64) return;
    int lane = idx & 63;
    int chunk = (idx >> 6) & 3;
    int tap = idx >> 8;
    int co = lane & 15;
    int ci0 = chunk * 32 + (lane >> 4) * 8;
    short8 v;
#pragma unroll
    for (int j = 0; j < 8; ++j)
        v[j] = (co < 3) ? f2b(rgbw[((size_t)(co * CCH) + ci0 + j) * 9 + tap]) : (short)0;
    *reinterpret_cast<short8*>(&g_rgbpack[(size_t)idx * 8]) = v;
}

// ---------------- PixelNorm ----------------
__global__ void pixelnorm_kernel(const float* __restrict__ z)
{
    int b = blockIdx.x, lane = threadIdx.x;
    float v[8];
    float ss = 0.f;
#pragma unroll
    for (int u = 0; u < 8; ++u) { v[u] = z[b * D + u * 64 + lane]; ss += v[u] * v[u]; }
#pragma unroll
    for (int off = 32; off > 0; off >>= 1) ss += __shfl_xor(ss, off, 64);
    float r = rsqrtf(ss * (1.f / 512.f) + 1e-8f);
#pragma unroll
    for (int u = 0; u < 8; ++u) g_w[0][b * D + u * 64 + lane] = v[u] * r;
}

// ---------------- Mapping FC ----------------
__global__ __launch_bounds__(256) void map_fc_kernel(
    int srcSel, const float* __restrict__ W, const float* __restrict__ bias)
{
    const float* win = g_w[srcSel];
    float* wout = g_w[srcSel ^ 1];
    int b = blockIdx.y;
    int jb = blockIdx.x * 64;
    int tid = threadIdx.x;
    int jl = tid & 63, kp = tid >> 6;
    __shared__ float xin[D];
    __shared__ float part[4][64];
    for (int k = tid; k < D; k += 256) xin[k] = win[b * D + k];
    __syncthreads();
    float acc = 0.f;
    const float* Wp = W + jb + jl;
    for (int k = kp * 128; k < kp * 128 + 128; ++k) acc += xin[k] * Wp[(size_t)k * D];
    part[kp][jl] = acc;
    __syncthreads();
    if (tid < 64) {
        float s = part[0][tid] + part[1][tid] + part[2][tid] + part[3][tid] + bias[jb + tid];
        wout[b * D + jb + tid] = leaky(s);
    }
}

// ---------------- style + rstd (f32, matches reference demod exactly) ----------------
__global__ __launch_bounds__(256) void style_rstd_kernel(
    const float* __restrict__ Aw, const float* __restrict__ Ab,
    const float* __restrict__ convw)
{
    int b = blockIdx.y;
    int tid = threadIdx.x;
    __shared__ float st[CCH];
    __shared__ float part[256];
    {
        int c = tid & 127, half = tid >> 7;
        float a = 0.f;
        const float* wp = g_w[0] + b * D;
        for (int k = half * 256; k < half * 256 + 256; ++k) a += wp[k] * Aw[k * CCH + c];
        part[tid] = a;
    }
    __syncthreads();
    if (tid < CCH) {
        float s = part[tid] + part[tid + 128] + Ab[tid];
        st[tid] = s;
        if (blockIdx.x == 0) g_style[b * CCH + tid] = s;
    }
    __syncthreads();
    int col = tid >> 4;
    int kpart = tid & 15;
    int cout = blockIdx.x * 16 + col;
    float s = 0.f;
    const float* wp = convw + ((size_t)cout * CCH + kpart * 8) * 9;
#pragma unroll
    for (int ci = 0; ci < 8; ++ci) {
        float sv = st[kpart * 8 + ci];
#pragma unroll
        for (int k = 0; k < 9; ++k) { float m = wp[ci * 9 + k] * sv; s += m * m; }
    }
#pragma unroll
    for (int off = 8; off > 0; off >>= 1) s += __shfl_down(s, off, 16);
    if (kpart == 0) g_rstd[b * CCH + cout] = rsqrtf(s + 1e-8f);
}

// ---------------- layer 0 (x==0): out = leaky(noise*Bw + Bb), 4x4 ----------------
__global__ void layer0_kernel(const float* __restrict__ noise,
                              const float* __restrict__ Bw, const float* __restrict__ Bb)
{
    int idx = blockIdx.x * 256 + threadIdx.x;
    if (idx >= BS * CCH * 16) return;
    int pix = idx & 15;
    int c = (idx >> 4) & 127;
    int b = idx >> 11;
    float v = noise[b * 4096 + pix] * Bw[c] + Bb[c];
    g_bufA[((size_t)b * CCH + c) * 16 + pix] = leaky(v);
}

// ---------------- bilinear 2x upsample (jax half-pixel + boundary renorm) ----------------
__global__ void upsample_kernel(int srcSel, int Hin, int Win)
{
    const float* in = srcSel ? g_bufB : g_bufA;
    float* out = srcSel ? g_bufA : g_bufB;
    int Ho = Hin * 2, Wo = Win * 2;
    int total = BS * CCH * Ho * Wo;
    int idx = blockIdx.x * 256 + threadIdx.x;
    if (idx >= total) return;
    int x = idx % Wo;
    int y = (idx / Wo) % Ho;
    int bc = idx / (Wo * Ho);
    int my = y >> 1, mx = x >> 1;
    int y0, y1, x0, x1;
    float wy0, wy1, wx0, wx1;
    if ((y & 1) == 0) { y0 = my - 1; y1 = my; wy0 = 0.25f; wy1 = 0.75f; if (y0 < 0) { y0 = 0; wy0 = 0.f; wy1 = 1.f; } }
    else              { y0 = my; y1 = my + 1; wy0 = 0.75f; wy1 = 0.25f; if (y1 >= Hin) { y1 = Hin - 1; wy0 = 1.f; wy1 = 0.f; } }
    if ((x & 1) == 0) { x0 = mx - 1; x1 = mx; wx0 = 0.25f; wx1 = 0.75f; if (x0 < 0) { x0 = 0; wx0 = 0.f; wx1 = 1.f; } }
    else              { x0 = mx; x1 = mx + 1; wx0 = 0.75f; wx1 = 0.25f; if (x1 >= Win) { x1 = Win - 1; wx0 = 1.f; wx1 = 0.f; } }
    const float* p = in + (size_t)bc * Hin * Win;
    float v = wy0 * (wx0 * p[y0 * Win + x0] + wx1 * p[y0 * Win + x1])
            + wy1 * (wx0 * p[y1 * Win + x0] + wx1 * p[y1 * Win + x1]);
    out[idx] = v;
}

// ---------------- MFMA modulated conv ----------------
// Block: 64 px (full-width row band) x 64 co; 4 waves, wave = co-group of 16.
// LDS x tile bf16 [R+2][W+2][128ci], XOR-swizzle (^((col&7)<<3)) in short-index space.
// A-frag = packed weights (global/L2), B-frag = x from LDS; D[co][px]; f32 epilogue.
template<int LW>
__global__ __launch_bounds__(256) void conv_mfma_kernel(
    int srcSel, int layer,
    const float* __restrict__ noise,
    const float* __restrict__ Bw, const float* __restrict__ Bb)
{
    constexpr int W = 1 << LW;
    constexpr int R = 64 >> LW;
    constexpr int SW = W + 2;
    constexpr int ROWS = R + 2;
    constexpr int NS = W * W;

    const float* xin = srcSel ? g_bufB : g_bufA;
    float* xout = srcSel ? g_bufA : g_bufB;

    const int b = blockIdx.z;
    const int coTile = blockIdx.y;
    const int pixBase = blockIdx.x * 64;
    const int rowBase = pixBase >> LW;
    const int tid = threadIdx.x;
    const int lane = tid & 63;
    const int wave = tid >> 6;
    const int cogrp = coTile * 4 + wave;

    __shared__ short xs[ROWS * SW * CCH];
    __shared__ float style_s[CCH];

    if (tid < CCH) style_s[tid] = g_style[b * CCH + tid];
    __syncthreads();

    // ---- stage x (style-modulated bf16, swizzled); float4 granularity ----
    {
        const float* src = xin + (size_t)b * CCH * NS;
        constexpr int N4 = ROWS * CCH * (W >> 2);
        for (int idx = tid; idx < N4; idx += 256) {
            int cc = (idx & ((W >> 2) - 1)) << 2;
            int ci = (idx >> (LW - 2)) & 127;
            int rr = idx >> (LW - 2 + 7);
            int gy = rowBase + rr - 1;
            float4 v = make_float4(0.f, 0.f, 0.f, 0.f);
            if (gy >= 0 && gy < W)
                v = *reinterpret_cast<const float4*>(&src[ci * NS + gy * W + cc]);
            float sv = style_s[ci];
            int base = (rr * SW + cc + 1) * CCH + ci;
            xs[(base)           ^ (((cc + 1) & 7) << 3)] = f2b(v.x * sv);
            xs[(base + CCH)     ^ (((cc + 2) & 7) << 3)] = f2b(v.y * sv);
            xs[(base + 2 * CCH) ^ (((cc + 3) & 7) << 3)] = f2b(v.z * sv);
            xs[(base + 3 * CCH) ^ (((cc + 4) & 7) << 3)] = f2b(v.w * sv);
        }
        for (int idx = tid; idx < ROWS * CCH * 2; idx += 256) {
            int side = idx & 1;
            int ci = (idx >> 1) & 127;
            int rr = idx >> 8;
            int col = side ? (W + 1) : 0;
            xs[((rr * SW + col) * CCH + ci) ^ ((col & 7) << 3)] = 0;
        }
    }
    __syncthreads();

    int rL[4], cL[4];
#pragma unroll
    for (int pf = 0; pf < 4; ++pf) {
        int pl = pf * 16 + (lane & 15);
        cL[pf] = pl & (W - 1);
        rL[pf] = pl >> LW;
    }
    const int grpoff = (lane >> 4) * 8;

    f32x4 acc[4] = {};
    const short* wlane = g_wpack + ((size_t)layer * 9 * 4 * 8 * 64
                                    + (size_t)cogrp * 64 + lane) * 8;

    short8 wc = *reinterpret_cast<const short8*>(wlane);
#pragma unroll
    for (int k = 0; k < 36; ++k) {
        short8 wn = wc;
        if (k + 1 < 36)
            wn = *reinterpret_cast<const short8*>(wlane + (size_t)(k + 1) * 4096);
        const int tap = k >> 2, ch = k & 3;
        const int ky = tap / 3, kx = tap - ky * 3;
#pragma unroll
        for (int pf = 0; pf < 4; ++pf) {
            int col = cL[pf] + kx;
            int idx = (((rL[pf] + ky) * SW + col) * CCH + (ch << 5) + grpoff) ^ ((col & 7) << 3);
            short8 xf = *reinterpret_cast<const short8*>(&xs[idx]);
            acc[pf] = __builtin_amdgcn_mfma_f32_16x16x32_bf16(wc, xf, acc[pf], 0, 0, 0);
        }
        wc = wn;
    }

    // ---- epilogue: demod + noise + leaky (f32) ----
    const int coB = cogrp * 16 + (lane >> 4) * 4;
    float rs[4], bw[4], bb[4];
#pragma unroll
    for (int r = 0; r < 4; ++r) {
        rs[r] = g_rstd[b * CCH + coB + r];
        bw[r] = Bw[coB + r];
        bb[r] = Bb[coB + r];
    }
#pragma unroll
    for (int pf = 0; pf < 4; ++pf) {
        int px = pixBase + pf * 16 + (lane & 15);
        float nz = noise[b * 4096 + px];
#pragma unroll
        for (int r = 0; r < 4; ++r) {
            float v = acc[pf][r] * rs[r] + nz * bw[r] + bb[r];
            xout[(size_t)(b * CCH + coB + r) * NS + px] = leaky(v);
        }
    }
}

// ---------------- MFMA toRGB (W=64; 3 real rows in 16-row M tile; waves split K) ----------------
__global__ __launch_bounds__(256) void rgb_mfma_kernel(
    int srcSel, const float* __restrict__ rgbb, float* __restrict__ out)
{
    constexpr int W = 64, SW = 66, ROWS = 3, NS = 4096;
    const float* xin = srcSel ? g_bufB : g_bufA;

    const int b = blockIdx.z;
    const int pixBase = blockIdx.x * 64;
    const int rowBase = pixBase >> 6;
    const int tid = threadIdx.x;
    const int lane = tid & 63;
    const int wave = tid >> 6;     // K-chunk

    __shared__ short xs[ROWS * SW * CCH];

    {
        const float* src = xin + (size_t)b * CCH * NS;
        constexpr int N4 = ROWS * CCH * (W >> 2);
        for (int idx = tid; idx < N4; idx += 256) {
            int cc = (idx & 15) << 2;
            int ci = (idx >> 4) & 127;
            int rr = idx >> 11;
            int gy = rowBase + rr - 1;
            float4 v = make_float4(0.f, 0.f, 0.f, 0.f);
            if (gy >= 0 && gy < W)
                v = *reinterpret_cast<const float4*>(&src[ci * NS + gy * W + cc]);
            int base = (rr * SW + cc + 1) * CCH + ci;
            xs[(base)           ^ (((cc + 1) & 7) << 3)] = f2b(v.x);
            xs[(base + CCH)     ^ (((cc + 2) & 7) << 3)] = f2b(v.y);
            xs[(base + 2 * CCH) ^ (((cc + 3) & 7) << 3)] = f2b(v.z);
            xs[(base + 3 * CCH) ^ (((cc + 4) & 7) << 3)] = f2b(v.w);
        }
        for (int idx = tid; idx < ROWS * CCH * 2; idx += 256) {
            int side = idx & 1;
            int ci = (idx >> 1) & 127;
            int rr = idx >> 8;
            int col = side ? (W + 1) : 0;
            xs[((rr * SW + col) * CCH + ci) ^ ((col & 7) << 3)] = 0;
        }
    }
    __syncthreads();

    const int grpoff = (lane >> 4) * 8;
    const int cl = lane & 15;
    f32x4 acc[4] = {};
#pragma unroll
    for (int tap = 0; tap < 9; ++tap) {
        const int ky = tap / 3, kx = tap - ky * 3;
        short8 wf = *reinterpret_cast<const short8*>(
            &g_rgbpack[((size_t)(tap * 4 + wave) * 64 + lane) * 8]);
#pragma unroll
        for (int pf = 0; pf < 4; ++pf) {
            int col = cl + pf * 16 + kx;    // single output row per block
            int idx = ((ky * SW + col) * CCH + (wave << 5) + grpoff) ^ ((col & 7) << 3);
            short8 xf = *reinterpret_cast<const short8*>(&xs[idx]);
            acc[pf] = __builtin_amdgcn_mfma_f32_16x16x32_bf16(wf, xf, acc[pf], 0, 0, 0);
        }
    }
    __syncthreads();
    float* red = reinterpret_cast<float*>(xs);   // reuse LDS for K-reduction
    if (wave > 0) {
#pragma unroll
        for (int pf = 0; pf < 4; ++pf)
#pragma unroll
            for (int r = 0; r < 4; ++r)
                red[(((wave - 1) * 4 + pf) * 64 + lane) * 4 + r] = acc[pf][r];
    }
    __syncthreads();
    if (wave == 0 && (lane >> 4) == 0) {
#pragma unroll
        for (int pf = 0; pf < 4; ++pf) {
            int px = pixBase + pf * 16 + cl;
#pragma unroll
            for (int r = 0; r < 3; ++r) {
                float s = acc[pf][r];
#pragma unroll
                for (int wv = 0; wv < 3; ++wv)
                    s += red[((wv * 4 + pf) * 64 + lane) * 4 + r];
                out[(size_t)(b * 3 + r) * NS + px] = s + rgbb[r];
            }
        }
    }
}

// ---------------- launch ----------------
extern "C" void kernel_launch(void* const* d_in, const int* in_sizes, int n_in,
                              void* d_out, int out_size, void* d_ws, size_t ws_size,
                              hipStream_t stream)
{
    const float* latent = (const float*)d_in[0];
    const float* noise  = (const float*)d_in[1];
    const float* map_w  = (const float*)d_in[2];
    const float* map_b  = (const float*)d_in[3];
    const float* A_w    = (const float*)d_in[4];
    const float* A_b    = (const float*)d_in[5];
    const float* B_w    = (const float*)d_in[6];
    const float* B_b    = (const float*)d_in[7];
    const float* conv_w = (const float*)d_in[8];
    const float* rgb_w  = (const float*)d_in[9];
    const float* rgb_b  = (const float*)d_in[10];
    float* out = (float*)d_out;
    (void)d_ws; (void)ws_size;

    wprep_kernel<<<(NLAYERS * 9 * 4 * 8 * 64 + 255) / 256, 256, 0, stream>>>(conv_w);
    rgbprep_kernel<<<(9 * 4 * 64 + 255) / 256, 256, 0, stream>>>(rgb_w);

    pixelnorm_kernel<<<BS, 64, 0, stream>>>(latent);
    int wsel = 0;
    for (int i = 0; i < LMAP; ++i) {
        map_fc_kernel<<<dim3(8, BS), 256, 0, stream>>>(wsel, map_w + (size_t)i * D * D, map_b + i * D);
        wsel ^= 1;
    }

    layer0_kernel<<<(BS * CCH * 16 + 255) / 256, 256, 0, stream>>>(noise, B_w, B_b);

    int cur = 0;   // 0 => data in g_bufA
    int Hc = 4;
    for (int i = 1; i < NLAYERS; ++i) {
        if (i & 1) {
            int total = BS * CCH * Hc * 2 * Hc * 2;
            upsample_kernel<<<(total + 255) / 256, 256, 0, stream>>>(cur, Hc, Hc);
            Hc *= 2;
            cur ^= 1;
        }
        style_rstd_kernel<<<dim3(8, BS), 256, 0, stream>>>(
            A_w + (size_t)i * D * CCH, A_b + i * CCH,
            conv_w + (size_t)i * CCH * CCH * 9);
        int ns = Hc * Hc;
        dim3 grid(ns / 64, 2, BS);
        const float* nz = noise + (size_t)i * BS * 4096;
        switch (Hc) {
            case 8:  conv_mfma_kernel<3><<<grid, 256, 0, stream>>>(cur, i, nz, B_w + i * CCH, B_b + i * CCH); break;
            case 16: conv_mfma_kernel<4><<<grid, 256, 0, stream>>>(cur, i, nz, B_w + i * CCH, B_b + i * CCH); break;
            case 32: conv_mfma_kernel<5><<<grid, 256, 0, stream>>>(cur, i, nz, B_w + i * CCH, B_b + i * CCH); break;
            case 64: conv_mfma_kernel<6><<<grid, 256, 0, stream>>>(cur, i, nz, B_w + i * CCH, B_b + i * CCH); break;
        }
        cur ^= 1;
    }

    rgb_mfma_kernel<<<dim3(64, 1, BS), 256, 0, stream>>>(cur, rgb_b, out);
}

// Round 5
// 270.567 us; speedup vs baseline: 8.0814x; 2.9071x over previous
//
#include <hip/hip_runtime.h>
#include <hip/hip_bf16.h>

#define BS 8
#define D 512
#define CCH 128
#define LMAP 8
#define NLAYERS 9

typedef short short8 __attribute__((ext_vector_type(8)));
typedef float f32x4 __attribute__((ext_vector_type(4)));

// ---- module-global scratch ----
__device__ float g_bufA[(size_t)BS * CCH * 4096];   // 16.78 MB
__device__ float g_bufB[(size_t)BS * CCH * 4096];   // 16.78 MB
__device__ float g_w[2][BS * D];
__device__ float g_style_all[NLAYERS * BS * CCH];
__device__ float g_rstd_all[NLAYERS * BS * CCH];
// packed bf16 weight fragments: [layer][tap][chunk4][cogrp8][lane64][8]
__device__ short g_wpack[(size_t)NLAYERS * 9 * 4 * 8 * 64 * 8];   // 2.65 MB
// rgb: [tap][chunk4][lane64][8] (M=16 rows, rows 0-2 real)
__device__ short g_rgbpack[9 * 4 * 64 * 8];

__device__ __forceinline__ float leaky(float v) { return v >= 0.f ? v : 0.2f * v; }
__device__ __forceinline__ short f2b(float f) {
    __hip_bfloat16 h = __float2bfloat16(f);
    return *reinterpret_cast<short*>(&h);
}

// ---------------- weight fragment prep (all 9 layers) ----------------
__global__ __launch_bounds__(256) void wprep_kernel(const float* __restrict__ convw)
{
    int idx = blockIdx.x * 256 + threadIdx.x;        // [layer][tap][chunk][cogrp][lane]
    if (idx >= NLAYERS * 9 * 4 * 8 * 64) return;
    int lane = idx & 63;
    int cogrp = (idx >> 6) & 7;
    int chunk = (idx >> 9) & 3;
    int t = idx >> 11;           // layer*9 + tap
    int layer = t / 9, tap = t - layer * 9;
    int co = cogrp * 16 + (lane & 15);
    int ci0 = chunk * 32 + (lane >> 4) * 8;
    short8 v;
#pragma unroll
    for (int j = 0; j < 8; ++j)
        v[j] = f2b(convw[(((size_t)layer * CCH + co) * CCH + ci0 + j) * 9 + tap]);
    *reinterpret_cast<short8*>(&g_wpack[(size_t)idx * 8]) = v;
}

__global__ void rgbprep_kernel(const float* __restrict__ rgbw)
{
    int idx = blockIdx.x * 256 + threadIdx.x;        // [tap][chunk][lane]
    if (idx >= 9 * 4 * 64) return;
    int lane = idx & 63;
    int chunk = (idx >> 6) & 3;
    int tap = idx >> 8;
    int co = lane & 15;
    int ci0 = chunk * 32 + (lane >> 4) * 8;
    short8 v;
#pragma unroll
    for (int j = 0; j < 8; ++j)
        v[j] = (co < 3) ? f2b(rgbw[((size_t)(co * CCH) + ci0 + j) * 9 + tap]) : (short)0;
    *reinterpret_cast<short8*>(&g_rgbpack[(size_t)idx * 8]) = v;
}

// ---------------- PixelNorm ----------------
__global__ void pixelnorm_kernel(const float* __restrict__ z)
{
    int b = blockIdx.x, lane = threadIdx.x;
    float v[8];
    float ss = 0.f;
#pragma unroll
    for (int u = 0; u < 8; ++u) { v[u] = z[b * D + u * 64 + lane]; ss += v[u] * v[u]; }
#pragma unroll
    for (int off = 32; off > 0; off >>= 1) ss += __shfl_xor(ss, off, 64);
    float r = rsqrtf(ss * (1.f / 512.f) + 1e-8f);
#pragma unroll
    for (int u = 0; u < 8; ++u) g_w[0][b * D + u * 64 + lane] = v[u] * r;
}

// ---------------- Mapping FC (8-deep ILP: 8 loads in flight per thread) ----------------
__global__ __launch_bounds__(256) void map_fc_kernel(
    int srcSel, const float* __restrict__ W, const float* __restrict__ bias)
{
    const float* win = g_w[srcSel];
    float* wout = g_w[srcSel ^ 1];
    int b = blockIdx.y;
    int jb = blockIdx.x * 64;
    int tid = threadIdx.x;
    int jl = tid & 63, kp = tid >> 6;
    __shared__ float xin[D];
    __shared__ float part[4][64];
    for (int k = tid; k < D; k += 256) xin[k] = win[b * D + k];
    __syncthreads();
    const float* Wp = W + jb + jl;
    const int k0 = kp * 128;
    float a0 = 0.f, a1 = 0.f, a2 = 0.f, a3 = 0.f, a4 = 0.f, a5 = 0.f, a6 = 0.f, a7 = 0.f;
    for (int k = k0; k < k0 + 128; k += 8) {
        a0 += xin[k + 0] * Wp[(size_t)(k + 0) * D];
        a1 += xin[k + 1] * Wp[(size_t)(k + 1) * D];
        a2 += xin[k + 2] * Wp[(size_t)(k + 2) * D];
        a3 += xin[k + 3] * Wp[(size_t)(k + 3) * D];
        a4 += xin[k + 4] * Wp[(size_t)(k + 4) * D];
        a5 += xin[k + 5] * Wp[(size_t)(k + 5) * D];
        a6 += xin[k + 6] * Wp[(size_t)(k + 6) * D];
        a7 += xin[k + 7] * Wp[(size_t)(k + 7) * D];
    }
    part[kp][jl] = ((a0 + a1) + (a2 + a3)) + ((a4 + a5) + (a6 + a7));
    __syncthreads();
    if (tid < 64) {
        float s = part[0][tid] + part[1][tid] + part[2][tid] + part[3][tid] + bias[jb + tid];
        wout[b * D + jb + tid] = leaky(s);
    }
}

// ---------------- style for ALL layers: g_style_all[l][b][c] = w @ A_w[l] + A_b[l] ----------------
// grid (8 layers, BS); block 256 = 128 c x 2 k-halves; 8-deep ILP.
__global__ __launch_bounds__(256) void style_all_kernel(
    const float* __restrict__ Aw, const float* __restrict__ Ab)
{
    int l = blockIdx.x + 1;        // layers 1..8 (layer 0 unused: x==0)
    int b = blockIdx.y;
    int tid = threadIdx.x;
    int c = tid & 127, kh = tid >> 7;
    __shared__ float ws_[D];
    __shared__ float part[2][CCH];
    for (int k = tid; k < D; k += 256) ws_[k] = g_w[0][b * D + k];
    __syncthreads();
    const float* Ap = Aw + (size_t)l * D * CCH + c;
    const int k0 = kh * 256;
    float a0 = 0.f, a1 = 0.f, a2 = 0.f, a3 = 0.f, a4 = 0.f, a5 = 0.f, a6 = 0.f, a7 = 0.f;
    for (int k = k0; k < k0 + 256; k += 8) {
        a0 += ws_[k + 0] * Ap[(size_t)(k + 0) * CCH];
        a1 += ws_[k + 1] * Ap[(size_t)(k + 1) * CCH];
        a2 += ws_[k + 2] * Ap[(size_t)(k + 2) * CCH];
        a3 += ws_[k + 3] * Ap[(size_t)(k + 3) * CCH];
        a4 += ws_[k + 4] * Ap[(size_t)(k + 4) * CCH];
        a5 += ws_[k + 5] * Ap[(size_t)(k + 5) * CCH];
        a6 += ws_[k + 6] * Ap[(size_t)(k + 6) * CCH];
        a7 += ws_[k + 7] * Ap[(size_t)(k + 7) * CCH];
    }
    part[kh][c] = ((a0 + a1) + (a2 + a3)) + ((a4 + a5) + (a6 + a7));
    __syncthreads();
    if (tid < CCH)
        g_style_all[((size_t)l * BS + b) * CCH + tid] =
            part[0][tid] + part[1][tid] + Ab[l * CCH + tid];
}

// ---------------- rstd for ALL layers ----------------
// grid (8 cogrp, 8 layers, BS) = 512 blocks; block 256 = 16 co x 16 ci-parts.
// Each thread: 72 consecutive convw floats as 18 independent float4 loads.
__global__ __launch_bounds__(256) void rstd_all_kernel(const float* __restrict__ convw)
{
    int cogrp = blockIdx.x;
    int l = blockIdx.y + 1;        // 1..8
    int b = blockIdx.z;
    int tid = threadIdx.x;
    int col = tid >> 4, kpart = tid & 15;
    int cout = cogrp * 16 + col;
    __shared__ float st[CCH];
    if (tid < CCH) st[tid] = g_style_all[((size_t)l * BS + b) * CCH + tid];
    __syncthreads();
    const float* wp = convw + ((size_t)(l * CCH + cout) * CCH + kpart * 8) * 9;
    float wf[72];
#pragma unroll
    for (int q = 0; q < 18; ++q) {
        float4 t = *reinterpret_cast<const float4*>(wp + q * 4);
        wf[q * 4 + 0] = t.x; wf[q * 4 + 1] = t.y; wf[q * 4 + 2] = t.z; wf[q * 4 + 3] = t.w;
    }
    float s = 0.f;
#pragma unroll
    for (int ci = 0; ci < 8; ++ci) {
        float sv = st[kpart * 8 + ci];
#pragma unroll
        for (int k = 0; k < 9; ++k) { float m = wf[ci * 9 + k] * sv; s += m * m; }
    }
#pragma unroll
    for (int off = 8; off > 0; off >>= 1) s += __shfl_down(s, off, 16);
    if (kpart == 0) g_rstd_all[((size_t)l * BS + b) * CCH + cout] = rsqrtf(s + 1e-8f);
}

// ---------------- layer 0 (x==0): out = leaky(noise*Bw + Bb), 4x4 ----------------
__global__ void layer0_kernel(const float* __restrict__ noise,
                              const float* __restrict__ Bw, const float* __restrict__ Bb)
{
    int idx = blockIdx.x * 256 + threadIdx.x;
    if (idx >= BS * CCH * 16) return;
    int pix = idx & 15;
    int c = (idx >> 4) & 127;
    int b = idx >> 11;
    float v = noise[b * 4096 + pix] * Bw[c] + Bb[c];
    g_bufA[((size_t)b * CCH + c) * 16 + pix] = leaky(v);
}

// ---------------- bilinear 2x upsample (jax half-pixel + boundary renorm) ----------------
__global__ void upsample_kernel(int srcSel, int Hin, int Win)
{
    const float* in = srcSel ? g_bufB : g_bufA;
    float* out = srcSel ? g_bufA : g_bufB;
    int Ho = Hin * 2, Wo = Win * 2;
    int total = BS * CCH * Ho * Wo;
    int idx = blockIdx.x * 256 + threadIdx.x;
    if (idx >= total) return;
    int x = idx % Wo;
    int y = (idx / Wo) % Ho;
    int bc = idx / (Wo * Ho);
    int my = y >> 1, mx = x >> 1;
    int y0, y1, x0, x1;
    float wy0, wy1, wx0, wx1;
    if ((y & 1) == 0) { y0 = my - 1; y1 = my; wy0 = 0.25f; wy1 = 0.75f; if (y0 < 0) { y0 = 0; wy0 = 0.f; wy1 = 1.f; } }
    else              { y0 = my; y1 = my + 1; wy0 = 0.75f; wy1 = 0.25f; if (y1 >= Hin) { y1 = Hin - 1; wy0 = 1.f; wy1 = 0.f; } }
    if ((x & 1) == 0) { x0 = mx - 1; x1 = mx; wx0 = 0.25f; wx1 = 0.75f; if (x0 < 0) { x0 = 0; wx0 = 0.f; wx1 = 1.f; } }
    else              { x0 = mx; x1 = mx + 1; wx0 = 0.75f; wx1 = 0.25f; if (x1 >= Win) { x1 = Win - 1; wx0 = 1.f; wx1 = 0.f; } }
    const float* p = in + (size_t)bc * Hin * Win;
    float v = wy0 * (wx0 * p[y0 * Win + x0] + wx1 * p[y0 * Win + x1])
            + wy1 * (wx0 * p[y1 * Win + x0] + wx1 * p[y1 * Win + x1]);
    out[idx] = v;
}

// ---------------- MFMA modulated conv ----------------
// Block: 64 px (full-width row band) x 64 co; 4 waves, wave = co-group of 16.
// LDS x tile bf16 [R+2][W+2][128ci], XOR-swizzle (^((col&7)<<3)) in short-index space.
template<int LW>
__global__ __launch_bounds__(256) void conv_mfma_kernel(
    int srcSel, int layer,
    const float* __restrict__ noise,
    const float* __restrict__ Bw, const float* __restrict__ Bb)
{
    constexpr int W = 1 << LW;
    constexpr int R = 64 >> LW;
    constexpr int SW = W + 2;
    constexpr int ROWS = R + 2;
    constexpr int NS = W * W;

    const float* xin = srcSel ? g_bufB : g_bufA;
    float* xout = srcSel ? g_bufA : g_bufB;

    const int b = blockIdx.z;
    const int coTile = blockIdx.y;
    const int pixBase = blockIdx.x * 64;
    const int rowBase = pixBase >> LW;
    const int tid = threadIdx.x;
    const int lane = tid & 63;
    const int wave = tid >> 6;
    const int cogrp = coTile * 4 + wave;

    __shared__ short xs[ROWS * SW * CCH];
    __shared__ float style_s[CCH];

    if (tid < CCH) style_s[tid] = g_style_all[((size_t)layer * BS + b) * CCH + tid];
    __syncthreads();

    // ---- stage x (style-modulated bf16, swizzled); float4 granularity ----
    {
        const float* src = xin + (size_t)b * CCH * NS;
        constexpr int N4 = ROWS * CCH * (W >> 2);
        for (int idx = tid; idx < N4; idx += 256) {
            int cc = (idx & ((W >> 2) - 1)) << 2;
            int ci = (idx >> (LW - 2)) & 127;
            int rr = idx >> (LW - 2 + 7);
            int gy = rowBase + rr - 1;
            float4 v = make_float4(0.f, 0.f, 0.f, 0.f);
            if (gy >= 0 && gy < W)
                v = *reinterpret_cast<const float4*>(&src[ci * NS + gy * W + cc]);
            float sv = style_s[ci];
            int base = (rr * SW + cc + 1) * CCH + ci;
            xs[(base)           ^ (((cc + 1) & 7) << 3)] = f2b(v.x * sv);
            xs[(base + CCH)     ^ (((cc + 2) & 7) << 3)] = f2b(v.y * sv);
            xs[(base + 2 * CCH) ^ (((cc + 3) & 7) << 3)] = f2b(v.z * sv);
            xs[(base + 3 * CCH) ^ (((cc + 4) & 7) << 3)] = f2b(v.w * sv);
        }
        for (int idx = tid; idx < ROWS * CCH * 2; idx += 256) {
            int side = idx & 1;
            int ci = (idx >> 1) & 127;
            int rr = idx >> 8;
            int col = side ? (W + 1) : 0;
            xs[((rr * SW + col) * CCH + ci) ^ ((col & 7) << 3)] = 0;
        }
    }
    __syncthreads();

    int rL[4], cL[4];
#pragma unroll
    for (int pf = 0; pf < 4; ++pf) {
        int pl = pf * 16 + (lane & 15);
        cL[pf] = pl & (W - 1);
        rL[pf] = pl >> LW;
    }
    const int grpoff = (lane >> 4) * 8;

    f32x4 acc[4] = {};
    const short* wlane = g_wpack + ((size_t)layer * 9 * 4 * 8 * 64
                                    + (size_t)cogrp * 64 + lane) * 8;

    short8 wc = *reinterpret_cast<const short8*>(wlane);
#pragma unroll
    for (int k = 0; k < 36; ++k) {
        short8 wn = wc;
        if (k + 1 < 36)
            wn = *reinterpret_cast<const short8*>(wlane + (size_t)(k + 1) * 4096);
        const int tap = k >> 2, ch = k & 3;
        const int ky = tap / 3, kx = tap - ky * 3;
#pragma unroll
        for (int pf = 0; pf < 4; ++pf) {
            int col = cL[pf] + kx;
            int idx = (((rL[pf] + ky) * SW + col) * CCH + (ch << 5) + grpoff) ^ ((col & 7) << 3);
            short8 xf = *reinterpret_cast<const short8*>(&xs[idx]);
            acc[pf] = __builtin_amdgcn_mfma_f32_16x16x32_bf16(wc, xf, acc[pf], 0, 0, 0);
        }
        wc = wn;
    }

    // ---- epilogue: demod + noise + leaky (f32) ----
    const int coB = cogrp * 16 + (lane >> 4) * 4;
    float rs[4], bw[4], bb[4];
#pragma unroll
    for (int r = 0; r < 4; ++r) {
        rs[r] = g_rstd_all[((size_t)layer * BS + b) * CCH + coB + r];
        bw[r] = Bw[coB + r];
        bb[r] = Bb[coB + r];
    }
#pragma unroll
    for (int pf = 0; pf < 4; ++pf) {
        int px = pixBase + pf * 16 + (lane & 15);
        float nz = noise[b * 4096 + px];
#pragma unroll
        for (int r = 0; r < 4; ++r) {
            float v = acc[pf][r] * rs[r] + nz * bw[r] + bb[r];
            xout[(size_t)(b * CCH + coB + r) * NS + px] = leaky(v);
        }
    }
}

// ---------------- MFMA toRGB (W=64; 3 real rows in 16-row M tile; waves split K) ----------------
__global__ __launch_bounds__(256) void rgb_mfma_kernel(
    int srcSel, const float* __restrict__ rgbb, float* __restrict__ out)
{
    constexpr int W = 64, SW = 66, ROWS = 3, NS = 4096;
    const float* xin = srcSel ? g_bufB : g_bufA;

    const int b = blockIdx.z;
    const int pixBase = blockIdx.x * 64;
    const int rowBase = pixBase >> 6;
    const int tid = threadIdx.x;
    const int lane = tid & 63;
    const int wave = tid >> 6;     // K-chunk

    __shared__ short xs[ROWS * SW * CCH];

    {
        const float* src = xin + (size_t)b * CCH * NS;
        constexpr int N4 = ROWS * CCH * (W >> 2);
        for (int idx = tid; idx < N4; idx += 256) {
            int cc = (idx & 15) << 2;
            int ci = (idx >> 4) & 127;
            int rr = idx >> 11;
            int gy = rowBase + rr - 1;
            float4 v = make_float4(0.f, 0.f, 0.f, 0.f);
            if (gy >= 0 && gy < W)
                v = *reinterpret_cast<const float4*>(&src[ci * NS + gy * W + cc]);
            int base = (rr * SW + cc + 1) * CCH + ci;
            xs[(base)           ^ (((cc + 1) & 7) << 3)] = f2b(v.x);
            xs[(base + CCH)     ^ (((cc + 2) & 7) << 3)] = f2b(v.y);
            xs[(base + 2 * CCH) ^ (((cc + 3) & 7) << 3)] = f2b(v.z);
            xs[(base + 3 * CCH) ^ (((cc + 4) & 7) << 3)] = f2b(v.w);
        }
        for (int idx = tid; idx < ROWS * CCH * 2; idx += 256) {
            int side = idx & 1;
            int ci = (idx >> 1) & 127;
            int rr = idx >> 8;
            int col = side ? (W + 1) : 0;
            xs[((rr * SW + col) * CCH + ci) ^ ((col & 7) << 3)] = 0;
        }
    }
    __syncthreads();

    const int grpoff = (lane >> 4) * 8;
    const int cl = lane & 15;
    f32x4 acc[4] = {};
#pragma unroll
    for (int tap = 0; tap < 9; ++tap) {
        const int ky = tap / 3, kx = tap - ky * 3;
        short8 wf = *reinterpret_cast<const short8*>(
            &g_rgbpack[((size_t)(tap * 4 + wave) * 64 + lane) * 8]);
#pragma unroll
        for (int pf = 0; pf < 4; ++pf) {
            int col = cl + pf * 16 + kx;
            int idx = ((ky * SW + col) * CCH + (wave << 5) + grpoff) ^ ((col & 7) << 3);
            short8 xf = *reinterpret_cast<const short8*>(&xs[idx]);
            acc[pf] = __builtin_amdgcn_mfma_f32_16x16x32_bf16(wf, xf, acc[pf], 0, 0, 0);
        }
    }
    __syncthreads();
    float* red = reinterpret_cast<float*>(xs);   // reuse LDS for K-reduction
    if (wave > 0) {
#pragma unroll
        for (int pf = 0; pf < 4; ++pf)
#pragma unroll
            for (int r = 0; r < 4; ++r)
                red[(((wave - 1) * 4 + pf) * 64 + lane) * 4 + r] = acc[pf][r];
    }
    __syncthreads();
    if (wave == 0 && (lane >> 4) == 0) {
#pragma unroll
        for (int pf = 0; pf < 4; ++pf) {
            int px = pixBase + pf * 16 + cl;
#pragma unroll
            for (int r = 0; r < 3; ++r) {
                float s = acc[pf][r];
#pragma unroll
                for (int wv = 0; wv < 3; ++wv)
                    s += red[((wv * 4 + pf) * 64 + lane) * 4 + r];
                out[(size_t)(b * 3 + r) * NS + px] = s + rgbb[r];
            }
        }
    }
}

// ---------------- launch ----------------
extern "C" void kernel_launch(void* const* d_in, const int* in_sizes, int n_in,
                              void* d_out, int out_size, void* d_ws, size_t ws_size,
                              hipStream_t stream)
{
    const float* latent = (const float*)d_in[0];
    const float* noise  = (const float*)d_in[1];
    const float* map_w  = (const float*)d_in[2];
    const float* map_b  = (const float*)d_in[3];
    const float* A_w    = (const float*)d_in[4];
    const float* A_b    = (const float*)d_in[5];
    const float* B_w    = (const float*)d_in[6];
    const float* B_b    = (const float*)d_in[7];
    const float* conv_w = (const float*)d_in[8];
    const float* rgb_w  = (const float*)d_in[9];
    const float* rgb_b  = (const float*)d_in[10];
    float* out = (float*)d_out;
    (void)d_ws; (void)ws_size;

    wprep_kernel<<<(NLAYERS * 9 * 4 * 8 * 64 + 255) / 256, 256, 0, stream>>>(conv_w);
    rgbprep_kernel<<<(9 * 4 * 64 + 255) / 256, 256, 0, stream>>>(rgb_w);

    pixelnorm_kernel<<<BS, 64, 0, stream>>>(latent);
    int wsel = 0;
    for (int i = 0; i < LMAP; ++i) {
        map_fc_kernel<<<dim3(8, BS), 256, 0, stream>>>(wsel, map_w + (size_t)i * D * D, map_b + i * D);
        wsel ^= 1;
    }

    // style + rstd for all layers in 2 dispatches
    style_all_kernel<<<dim3(8, BS), 256, 0, stream>>>(A_w, A_b);
    rstd_all_kernel<<<dim3(8, 8, BS), 256, 0, stream>>>(conv_w);

    layer0_kernel<<<(BS * CCH * 16 + 255) / 256, 256, 0, stream>>>(noise, B_w, B_b);

    int cur = 0;   // 0 => data in g_bufA
    int Hc = 4;
    for (int i = 1; i < NLAYERS; ++i) {
        if (i & 1) {
            int total = BS * CCH * Hc * 2 * Hc * 2;
            upsample_kernel<<<(total + 255) / 256, 256, 0, stream>>>(cur, Hc, Hc);
            Hc *= 2;
            cur ^= 1;
        }
        int ns = Hc * Hc;
        dim3 grid(ns / 64, 2, BS);
        const float* nz = noise + (size_t)i * BS * 4096;
        switch (Hc) {
            case 8:  conv_mfma_kernel<3><<<grid, 256, 0, stream>>>(cur, i, nz, B_w + i * CCH, B_b + i * CCH); break;
            case 16: conv_mfma_kernel<4><<<grid, 256, 0, stream>>>(cur, i, nz, B_w + i * CCH, B_b + i * CCH); break;
            case 32: conv_mfma_kernel<5><<<grid, 256, 0, stream>>>(cur, i, nz, B_w + i * CCH, B_b + i * CCH); break;
            case 64: conv_mfma_kernel<6><<<grid, 256, 0, stream>>>(cur, i, nz, B_w + i * CCH, B_b + i * CCH); break;
        }
        cur ^= 1;
    }

    rgb_mfma_kernel<<<dim3(64, 1, BS), 256, 0, stream>>>(cur, rgb_b, out);
}

// Round 6
// 247.758 us; speedup vs baseline: 8.8254x; 1.0921x over previous
//
#include <hip/hip_runtime.h>
#include <hip/hip_bf16.h>

#define BS 8
#define D 512
#define CCH 128
#define LMAP 8
#define NLAYERS 9

typedef short short8 __attribute__((ext_vector_type(8)));
typedef float f32x4 __attribute__((ext_vector_type(4)));

// ---- module-global scratch ----
__device__ float g_bufA[(size_t)BS * CCH * 4096];   // 16.78 MB
__device__ float g_bufB[(size_t)BS * CCH * 4096];   // 16.78 MB
__device__ float g_w[2][BS * D];
__device__ float g_style_all[NLAYERS * BS * CCH];
__device__ float g_rstd_all[NLAYERS * BS * CCH];
// packed bf16 weight fragments: [layer][tap][chunk4][cogrp8][lane64][8]
__device__ short g_wpack[(size_t)NLAYERS * 9 * 4 * 8 * 64 * 8];   // 2.65 MB
// rgb: [tap][chunk4][lane64][8] (M=16 rows, rows 0-2 real)
__device__ short g_rgbpack[9 * 4 * 64 * 8];

__device__ __forceinline__ float leaky(float v) { return v >= 0.f ? v : 0.2f * v; }
__device__ __forceinline__ short f2b(float f) {
    __hip_bfloat16 h = __float2bfloat16(f);
    return *reinterpret_cast<short*>(&h);
}
// bank swizzle: XOR on short-index bits 3..5; conflict-free for col-step 1 (reads)
// AND col-step 4 (staging writes). Bijective within ci (ci < 128 uses bits 0..6).
__device__ __forceinline__ int swz(int col) { return ((col ^ (col >> 3)) & 7) << 3; }

// ---------------- weight fragment prep (all 9 layers) ----------------
__global__ __launch_bounds__(256) void wprep_kernel(const float* __restrict__ convw)
{
    int idx = blockIdx.x * 256 + threadIdx.x;        // [layer][tap][chunk][cogrp][lane]
    if (idx >= NLAYERS * 9 * 4 * 8 * 64) return;
    int lane = idx & 63;
    int cogrp = (idx >> 6) & 7;
    int chunk = (idx >> 9) & 3;
    int t = idx >> 11;           // layer*9 + tap
    int layer = t / 9, tap = t - layer * 9;
    int co = cogrp * 16 + (lane & 15);
    int ci0 = chunk * 32 + (lane >> 4) * 8;
    short8 v;
#pragma unroll
    for (int j = 0; j < 8; ++j)
        v[j] = f2b(convw[(((size_t)layer * CCH + co) * CCH + ci0 + j) * 9 + tap]);
    *reinterpret_cast<short8*>(&g_wpack[(size_t)idx * 8]) = v;
}

__global__ void rgbprep_kernel(const float* __restrict__ rgbw)
{
    int idx = blockIdx.x * 256 + threadIdx.x;        // [tap][chunk][lane]
    if (idx >= 9 * 4 * 64) return;
    int lane = idx & 63;
    int chunk = (idx >> 6) & 3;
    int tap = idx >> 8;
    int co = lane & 15;
    int ci0 = chunk * 32 + (lane >> 4) * 8;
    short8 v;
#pragma unroll
    for (int j = 0; j < 8; ++j)
        v[j] = (co < 3) ? f2b(rgbw[((size_t)(co * CCH) + ci0 + j) * 9 + tap]) : (short)0;
    *reinterpret_cast<short8*>(&g_rgbpack[(size_t)idx * 8]) = v;
}

// ---------------- PixelNorm ----------------
__global__ void pixelnorm_kernel(const float* __restrict__ z)
{
    int b = blockIdx.x, lane = threadIdx.x;
    float v[8];
    float ss = 0.f;
#pragma unroll
    for (int u = 0; u < 8; ++u) { v[u] = z[b * D + u * 64 + lane]; ss += v[u] * v[u]; }
#pragma unroll
    for (int off = 32; off > 0; off >>= 1) ss += __shfl_xor(ss, off, 64);
    float r = rsqrtf(ss * (1.f / 512.f) + 1e-8f);
#pragma unroll
    for (int u = 0; u < 8; ++u) g_w[0][b * D + u * 64 + lane] = v[u] * r;
}

// ---------------- Mapping FC (8-deep ILP) ----------------
__global__ __launch_bounds__(256) void map_fc_kernel(
    int srcSel, const float* __restrict__ W, const float* __restrict__ bias)
{
    const float* win = g_w[srcSel];
    float* wout = g_w[srcSel ^ 1];
    int b = blockIdx.y;
    int jb = blockIdx.x * 64;
    int tid = threadIdx.x;
    int jl = tid & 63, kp = tid >> 6;
    __shared__ float xin[D];
    __shared__ float part[4][64];
    for (int k = tid; k < D; k += 256) xin[k] = win[b * D + k];
    __syncthreads();
    const float* Wp = W + jb + jl;
    const int k0 = kp * 128;
    float a0 = 0.f, a1 = 0.f, a2 = 0.f, a3 = 0.f, a4 = 0.f, a5 = 0.f, a6 = 0.f, a7 = 0.f;
    for (int k = k0; k < k0 + 128; k += 8) {
        a0 += xin[k + 0] * Wp[(size_t)(k + 0) * D];
        a1 += xin[k + 1] * Wp[(size_t)(k + 1) * D];
        a2 += xin[k + 2] * Wp[(size_t)(k + 2) * D];
        a3 += xin[k + 3] * Wp[(size_t)(k + 3) * D];
        a4 += xin[k + 4] * Wp[(size_t)(k + 4) * D];
        a5 += xin[k + 5] * Wp[(size_t)(k + 5) * D];
        a6 += xin[k + 6] * Wp[(size_t)(k + 6) * D];
        a7 += xin[k + 7] * Wp[(size_t)(k + 7) * D];
    }
    part[kp][jl] = ((a0 + a1) + (a2 + a3)) + ((a4 + a5) + (a6 + a7));
    __syncthreads();
    if (tid < 64) {
        float s = part[0][tid] + part[1][tid] + part[2][tid] + part[3][tid] + bias[jb + tid];
        wout[b * D + jb + tid] = leaky(s);
    }
}

// ---------------- style for ALL layers ----------------
__global__ __launch_bounds__(256) void style_all_kernel(
    const float* __restrict__ Aw, const float* __restrict__ Ab)
{
    int l = blockIdx.x + 1;        // layers 1..8
    int b = blockIdx.y;
    int tid = threadIdx.x;
    int c = tid & 127, kh = tid >> 7;
    __shared__ float ws_[D];
    __shared__ float part[2][CCH];
    for (int k = tid; k < D; k += 256) ws_[k] = g_w[0][b * D + k];
    __syncthreads();
    const float* Ap = Aw + (size_t)l * D * CCH + c;
    const int k0 = kh * 256;
    float a0 = 0.f, a1 = 0.f, a2 = 0.f, a3 = 0.f, a4 = 0.f, a5 = 0.f, a6 = 0.f, a7 = 0.f;
    for (int k = k0; k < k0 + 256; k += 8) {
        a0 += ws_[k + 0] * Ap[(size_t)(k + 0) * CCH];
        a1 += ws_[k + 1] * Ap[(size_t)(k + 1) * CCH];
        a2 += ws_[k + 2] * Ap[(size_t)(k + 2) * CCH];
        a3 += ws_[k + 3] * Ap[(size_t)(k + 3) * CCH];
        a4 += ws_[k + 4] * Ap[(size_t)(k + 4) * CCH];
        a5 += ws_[k + 5] * Ap[(size_t)(k + 5) * CCH];
        a6 += ws_[k + 6] * Ap[(size_t)(k + 6) * CCH];
        a7 += ws_[k + 7] * Ap[(size_t)(k + 7) * CCH];
    }
    part[kh][c] = ((a0 + a1) + (a2 + a3)) + ((a4 + a5) + (a6 + a7));
    __syncthreads();
    if (tid < CCH)
        g_style_all[((size_t)l * BS + b) * CCH + tid] =
            part[0][tid] + part[1][tid] + Ab[l * CCH + tid];
}

// ---------------- rstd for ALL layers ----------------
__global__ __launch_bounds__(256) void rstd_all_kernel(const float* __restrict__ convw)
{
    int cogrp = blockIdx.x;
    int l = blockIdx.y + 1;        // 1..8
    int b = blockIdx.z;
    int tid = threadIdx.x;
    int col = tid >> 4, kpart = tid & 15;
    int cout = cogrp * 16 + col;
    __shared__ float st[CCH];
    if (tid < CCH) st[tid] = g_style_all[((size_t)l * BS + b) * CCH + tid];
    __syncthreads();
    const float* wp = convw + ((size_t)(l * CCH + cout) * CCH + kpart * 8) * 9;
    float wf[72];
#pragma unroll
    for (int q = 0; q < 18; ++q) {
        float4 t = *reinterpret_cast<const float4*>(wp + q * 4);
        wf[q * 4 + 0] = t.x; wf[q * 4 + 1] = t.y; wf[q * 4 + 2] = t.z; wf[q * 4 + 3] = t.w;
    }
    float s = 0.f;
#pragma unroll
    for (int ci = 0; ci < 8; ++ci) {
        float sv = st[kpart * 8 + ci];
#pragma unroll
        for (int k = 0; k < 9; ++k) { float m = wf[ci * 9 + k] * sv; s += m * m; }
    }
#pragma unroll
    for (int off = 8; off > 0; off >>= 1) s += __shfl_down(s, off, 16);
    if (kpart == 0) g_rstd_all[((size_t)l * BS + b) * CCH + cout] = rsqrtf(s + 1e-8f);
}

// ---------------- layer 0 (x==0): out = leaky(noise*Bw + Bb), 4x4 ----------------
__global__ void layer0_kernel(const float* __restrict__ noise,
                              const float* __restrict__ Bw, const float* __restrict__ Bb)
{
    int idx = blockIdx.x * 256 + threadIdx.x;
    if (idx >= BS * CCH * 16) return;
    int pix = idx & 15;
    int c = (idx >> 4) & 127;
    int b = idx >> 11;
    float v = noise[b * 4096 + pix] * Bw[c] + Bb[c];
    g_bufA[((size_t)b * CCH + c) * 16 + pix] = leaky(v);
}

// ---------------- bilinear 2x upsample (jax half-pixel + boundary renorm) ----------------
__global__ void upsample_kernel(int srcSel, int Hin, int Win)
{
    const float* in = srcSel ? g_bufB : g_bufA;
    float* out = srcSel ? g_bufA : g_bufB;
    int Ho = Hin * 2, Wo = Win * 2;
    int total = BS * CCH * Ho * Wo;
    int idx = blockIdx.x * 256 + threadIdx.x;
    if (idx >= total) return;
    int x = idx % Wo;
    int y = (idx / Wo) % Ho;
    int bc = idx / (Wo * Ho);
    int my = y >> 1, mx = x >> 1;
    int y0, y1, x0, x1;
    float wy0, wy1, wx0, wx1;
    if ((y & 1) == 0) { y0 = my - 1; y1 = my; wy0 = 0.25f; wy1 = 0.75f; if (y0 < 0) { y0 = 0; wy0 = 0.f; wy1 = 1.f; } }
    else              { y0 = my; y1 = my + 1; wy0 = 0.75f; wy1 = 0.25f; if (y1 >= Hin) { y1 = Hin - 1; wy0 = 1.f; wy1 = 0.f; } }
    if ((x & 1) == 0) { x0 = mx - 1; x1 = mx; wx0 = 0.25f; wx1 = 0.75f; if (x0 < 0) { x0 = 0; wx0 = 0.f; wx1 = 1.f; } }
    else              { x0 = mx; x1 = mx + 1; wx0 = 0.75f; wx1 = 0.25f; if (x1 >= Win) { x1 = Win - 1; wx0 = 1.f; wx1 = 0.f; } }
    const float* p = in + (size_t)bc * Hin * Win;
    float v = wy0 * (wx0 * p[y0 * Win + x0] + wx1 * p[y0 * Win + x1])
            + wy1 * (wx0 * p[y1 * Win + x0] + wx1 * p[y1 * Win + x1]);
    out[idx] = v;
}

// ---------------- MFMA modulated conv ----------------
// Block: 64 px (full-width row band) x ALL 128 co; 4 waves; wave owns 2 co-frags (32 co).
// LDS x tile bf16 [R+2][W+2][128ci], swizzle ((col^(col>>3))&7)<<3 in short-index space.
template<int LW>
__global__ __launch_bounds__(256) void conv_mfma_kernel(
    int srcSel, int layer,
    const float* __restrict__ noise,
    const float* __restrict__ Bw, const float* __restrict__ Bb)
{
    constexpr int W = 1 << LW;
    constexpr int R = 64 >> LW;
    constexpr int SW = W + 2;
    constexpr int ROWS = R + 2;
    constexpr int NS = W * W;

    const float* xin = srcSel ? g_bufB : g_bufA;
    float* xout = srcSel ? g_bufA : g_bufB;

    const int b = blockIdx.y;
    const int pixBase = blockIdx.x * 64;
    const int rowBase = pixBase >> LW;
    const int tid = threadIdx.x;
    const int lane = tid & 63;
    const int wave = tid >> 6;

    __shared__ short xs[ROWS * SW * CCH];
    __shared__ float style_s[CCH];

    if (tid < CCH) style_s[tid] = g_style_all[((size_t)layer * BS + b) * CCH + tid];
    __syncthreads();

    // ---- stage x: style-modulated bf16, ci-pair packed short2 writes, swizzled ----
    {
        const float* src = xin + (size_t)b * CCH * NS;
        constexpr int U = ROWS * 64 * (W >> 2);
        for (int idx = tid; idx < U; idx += 256) {
            int ccg = idx & ((W >> 2) - 1);
            int cip = (idx >> (LW - 2)) & 63;
            int rr  = idx >> (LW - 2 + 6);
            int gy = rowBase + rr - 1;
            float4 v0 = make_float4(0.f, 0.f, 0.f, 0.f);
            float4 v1 = v0;
            if (gy >= 0 && gy < W) {
                v0 = *reinterpret_cast<const float4*>(&src[(size_t)(2 * cip) * NS + gy * W + ccg * 4]);
                v1 = *reinterpret_cast<const float4*>(&src[(size_t)(2 * cip + 1) * NS + gy * W + ccg * 4]);
            }
            float s0 = style_s[2 * cip], s1 = style_s[2 * cip + 1];
            int base = (rr * SW + ccg * 4 + 1) * CCH + 2 * cip;
            const float* p0 = reinterpret_cast<const float*>(&v0);
            const float* p1 = reinterpret_cast<const float*>(&v1);
#pragma unroll
            for (int j = 0; j < 4; ++j) {
                int col = ccg * 4 + 1 + j;
                short2 pk;
                pk.x = f2b(p0[j] * s0);
                pk.y = f2b(p1[j] * s1);
                *reinterpret_cast<short2*>(&xs[(base + j * CCH) ^ swz(col)]) = pk;
            }
        }
        // border columns 0 and W+1
        for (int idx = tid; idx < ROWS * 64 * 2; idx += 256) {
            int side = idx & 1;
            int cip = (idx >> 1) & 63;
            int rr = idx >> 7;
            int col = side ? (W + 1) : 0;
            short2 z; z.x = 0; z.y = 0;
            *reinterpret_cast<short2*>(&xs[(((rr * SW + col) * CCH) + 2 * cip) ^ swz(col)]) = z;
        }
    }
    __syncthreads();

    int rL[4], cL[4];
#pragma unroll
    for (int pf = 0; pf < 4; ++pf) {
        int pl = pf * 16 + (lane & 15);
        cL[pf] = pl & (W - 1);
        rL[pf] = pl >> LW;
    }
    const int grpoff = (lane >> 4) * 8;

    f32x4 acc[2][4] = {};
    const short* wl0 = g_wpack + ((size_t)layer * 9 * 4 * 8 * 64
                                  + (size_t)(wave * 2) * 64 + lane) * 8;
    const short* wl1 = wl0 + 64 * 8;

    short8 wc0 = *reinterpret_cast<const short8*>(wl0);
    short8 wc1 = *reinterpret_cast<const short8*>(wl1);
#pragma unroll
    for (int k = 0; k < 36; ++k) {
        short8 wn0 = wc0, wn1 = wc1;
        if (k + 1 < 36) {
            wn0 = *reinterpret_cast<const short8*>(wl0 + (size_t)(k + 1) * 4096);
            wn1 = *reinterpret_cast<const short8*>(wl1 + (size_t)(k + 1) * 4096);
        }
        const int tap = k >> 2, ch = k & 3;
        const int ky = tap / 3, kx = tap - ky * 3;
#pragma unroll
        for (int pf = 0; pf < 4; ++pf) {
            int col = cL[pf] + kx;
            int idx = (((rL[pf] + ky) * SW + col) * CCH + (ch << 5) + grpoff) ^ swz(col);
            short8 xf = *reinterpret_cast<const short8*>(&xs[idx]);
            acc[0][pf] = __builtin_amdgcn_mfma_f32_16x16x32_bf16(wc0, xf, acc[0][pf], 0, 0, 0);
            acc[1][pf] = __builtin_amdgcn_mfma_f32_16x16x32_bf16(wc1, xf, acc[1][pf], 0, 0, 0);
        }
        wc0 = wn0; wc1 = wn1;
    }

    // ---- epilogue: demod + noise + leaky (f32) ----
    float nz[4];
#pragma unroll
    for (int pf = 0; pf < 4; ++pf)
        nz[pf] = noise[b * 4096 + pixBase + pf * 16 + (lane & 15)];
#pragma unroll
    for (int cf = 0; cf < 2; ++cf) {
        const int coB = (wave * 2 + cf) * 16 + (lane >> 4) * 4;
        float rs[4], bw[4], bb[4];
#pragma unroll
        for (int r = 0; r < 4; ++r) {
            rs[r] = g_rstd_all[((size_t)layer * BS + b) * CCH + coB + r];
            bw[r] = Bw[coB + r];
            bb[r] = Bb[coB + r];
        }
#pragma unroll
        for (int pf = 0; pf < 4; ++pf) {
            int px = pixBase + pf * 16 + (lane & 15);
#pragma unroll
            for (int r = 0; r < 4; ++r) {
                float v = acc[cf][pf][r] * rs[r] + nz[pf] * bw[r] + bb[r];
                xout[(size_t)(b * CCH + coB + r) * NS + px] = leaky(v);
            }
        }
    }
}

// ---------------- MFMA toRGB (W=64; 3 real rows in 16-row M tile; waves split K) ----------------
__global__ __launch_bounds__(256) void rgb_mfma_kernel(
    int srcSel, const float* __restrict__ rgbb, float* __restrict__ out)
{
    constexpr int W = 64, SW = 66, ROWS = 3, NS = 4096;
    const float* xin = srcSel ? g_bufB : g_bufA;

    const int b = blockIdx.y;
    const int pixBase = blockIdx.x * 64;
    const int rowBase = pixBase >> 6;
    const int tid = threadIdx.x;
    const int lane = tid & 63;
    const int wave = tid >> 6;     // K-chunk

    __shared__ short xs[ROWS * SW * CCH];

    {
        const float* src = xin + (size_t)b * CCH * NS;
        constexpr int U = ROWS * 64 * 16;
        for (int idx = tid; idx < U; idx += 256) {
            int ccg = idx & 15;
            int cip = (idx >> 4) & 63;
            int rr  = idx >> 10;
            int gy = rowBase + rr - 1;
            float4 v0 = make_float4(0.f, 0.f, 0.f, 0.f);
            float4 v1 = v0;
            if (gy >= 0 && gy < W) {
                v0 = *reinterpret_cast<const float4*>(&src[(size_t)(2 * cip) * NS + gy * W + ccg * 4]);
                v1 = *reinterpret_cast<const float4*>(&src[(size_t)(2 * cip + 1) * NS + gy * W + ccg * 4]);
            }
            int base = (rr * SW + ccg * 4 + 1) * CCH + 2 * cip;
            const float* p0 = reinterpret_cast<const float*>(&v0);
            const float* p1 = reinterpret_cast<const float*>(&v1);
#pragma unroll
            for (int j = 0; j < 4; ++j) {
                int col = ccg * 4 + 1 + j;
                short2 pk;
                pk.x = f2b(p0[j]);
                pk.y = f2b(p1[j]);
                *reinterpret_cast<short2*>(&xs[(base + j * CCH) ^ swz(col)]) = pk;
            }
        }
        for (int idx = tid; idx < ROWS * 64 * 2; idx += 256) {
            int side = idx & 1;
            int cip = (idx >> 1) & 63;
            int rr = idx >> 7;
            int col = side ? (W + 1) : 0;
            short2 z; z.x = 0; z.y = 0;
            *reinterpret_cast<short2*>(&xs[(((rr * SW + col) * CCH) + 2 * cip) ^ swz(col)]) = z;
        }
    }
    __syncthreads();

    const int grpoff = (lane >> 4) * 8;
    const int cl = lane & 15;
    f32x4 acc[4] = {};
#pragma unroll
    for (int tap = 0; tap < 9; ++tap) {
        const int ky = tap / 3, kx = tap - ky * 3;
        short8 wf = *reinterpret_cast<const short8*>(
            &g_rgbpack[((size_t)(tap * 4 + wave) * 64 + lane) * 8]);
#pragma unroll
        for (int pf = 0; pf < 4; ++pf) {
            int col = cl + pf * 16 + kx;
            int idx = ((ky * SW + col) * CCH + (wave << 5) + grpoff) ^ swz(col);
            short8 xf = *reinterpret_cast<const short8*>(&xs[idx]);
            acc[pf] = __builtin_amdgcn_mfma_f32_16x16x32_bf16(wf, xf, acc[pf], 0, 0, 0);
        }
    }
    __syncthreads();
    float* red = reinterpret_cast<float*>(xs);   // reuse LDS for K-reduction
    if (wave > 0) {
#pragma unroll
        for (int pf = 0; pf < 4; ++pf)
#pragma unroll
            for (int r = 0; r < 4; ++r)
                red[(((wave - 1) * 4 + pf) * 64 + lane) * 4 + r] = acc[pf][r];
    }
    __syncthreads();
    if (wave == 0 && (lane >> 4) == 0) {
#pragma unroll
        for (int pf = 0; pf < 4; ++pf) {
            int px = pixBase + pf * 16 + cl;
#pragma unroll
            for (int r = 0; r < 3; ++r) {
                float s = acc[pf][r];
#pragma unroll
                for (int wv = 0; wv < 3; ++wv)
                    s += red[((wv * 4 + pf) * 64 + lane) * 4 + r];
                out[(size_t)(b * 3 + r) * NS + px] = s + rgbb[r];
            }
        }
    }
}

// ---------------- launch ----------------
extern "C" void kernel_launch(void* const* d_in, const int* in_sizes, int n_in,
                              void* d_out, int out_size, void* d_ws, size_t ws_size,
                              hipStream_t stream)
{
    const float* latent = (const float*)d_in[0];
    const float* noise  = (const float*)d_in[1];
    const float* map_w  = (const float*)d_in[2];
    const float* map_b  = (const float*)d_in[3];
    const float* A_w    = (const float*)d_in[4];
    const float* A_b    = (const float*)d_in[5];
    const float* B_w    = (const float*)d_in[6];
    const float* B_b    = (const float*)d_in[7];
    const float* conv_w = (const float*)d_in[8];
    const float* rgb_w  = (const float*)d_in[9];
    const float* rgb_b  = (const float*)d_in[10];
    float* out = (float*)d_out;
    (void)d_ws; (void)ws_size;

    wprep_kernel<<<(NLAYERS * 9 * 4 * 8 * 64 + 255) / 256, 256, 0, stream>>>(conv_w);
    rgbprep_kernel<<<(9 * 4 * 64 + 255) / 256, 256, 0, stream>>>(rgb_w);

    pixelnorm_kernel<<<BS, 64, 0, stream>>>(latent);
    int wsel = 0;
    for (int i = 0; i < LMAP; ++i) {
        map_fc_kernel<<<dim3(8, BS), 256, 0, stream>>>(wsel, map_w + (size_t)i * D * D, map_b + i * D);
        wsel ^= 1;
    }

    style_all_kernel<<<dim3(8, BS), 256, 0, stream>>>(A_w, A_b);
    rstd_all_kernel<<<dim3(8, 8, BS), 256, 0, stream>>>(conv_w);

    layer0_kernel<<<(BS * CCH * 16 + 255) / 256, 256, 0, stream>>>(noise, B_w, B_b);

    int cur = 0;   // 0 => data in g_bufA
    int Hc = 4;
    for (int i = 1; i < NLAYERS; ++i) {
        if (i & 1) {
            int total = BS * CCH * Hc * 2 * Hc * 2;
            upsample_kernel<<<(total + 255) / 256, 256, 0, stream>>>(cur, Hc, Hc);
            Hc *= 2;
            cur ^= 1;
        }
        int ns = Hc * Hc;
        dim3 grid(ns / 64, BS);
        const float* nz = noise + (size_t)i * BS * 4096;
        switch (Hc) {
            case 8:  conv_mfma_kernel<3><<<grid, 256, 0, stream>>>(cur, i, nz, B_w + i * CCH, B_b + i * CCH); break;
            case 16: conv_mfma_kernel<4><<<grid, 256, 0, stream>>>(cur, i, nz, B_w + i * CCH, B_b + i * CCH); break;
            case 32: conv_mfma_kernel<5><<<grid, 256, 0, stream>>>(cur, i, nz, B_w + i * CCH, B_b + i * CCH); break;
            case 64: conv_mfma_kernel<6><<<grid, 256, 0, stream>>>(cur, i, nz, B_w + i * CCH, B_b + i * CCH); break;
        }
        cur ^= 1;
    }

    rgb_mfma_kernel<<<dim3(64, BS), 256, 0, stream>>>(cur, rgb_b, out);
}

// Round 7
// 225.814 us; speedup vs baseline: 9.6830x; 1.0972x over previous
//
#include <hip/hip_runtime.h>
#include <hip/hip_bf16.h>

#define BS 8
#define D 512
#define CCH 128
#define LMAP 8
#define NLAYERS 9

typedef short short8 __attribute__((ext_vector_type(8)));
typedef short short4v __attribute__((ext_vector_type(4)));
typedef float f32x4 __attribute__((ext_vector_type(4)));

// ---- module-global scratch ----
// activations: bf16 NHWC [b][px][ci]
__device__ short g_bufA[(size_t)BS * 4096 * CCH];   // 8.4 MB
__device__ short g_bufB[(size_t)BS * 4096 * CCH];   // 8.4 MB
__device__ float g_w[2][BS * D];
__device__ float g_style_all[NLAYERS * BS * CCH];
__device__ float g_rstd_all[NLAYERS * BS * CCH];
// packed bf16 weight fragments: [layer][tap][chunk4][cogrp8][lane64][8]
__device__ short g_wpack[(size_t)NLAYERS * 9 * 4 * 8 * 64 * 8];   // 2.65 MB
// rgb: [tap][chunk4][lane64][8] (M=16 rows, rows 0-2 real)
__device__ short g_rgbpack[9 * 4 * 64 * 8];

__device__ __forceinline__ float leaky(float v) { return v >= 0.f ? v : 0.2f * v; }
__device__ __forceinline__ short f2b(float f) {
    __hip_bfloat16 h = __float2bfloat16(f);
    return *reinterpret_cast<short*>(&h);
}
__device__ __forceinline__ float b2f(short s) {
    return __uint_as_float(((unsigned int)(unsigned short)s) << 16);
}
// bank swizzle on short-index bits 3..5 (keeps 8-short blocks intact)
__device__ __forceinline__ int swz(int col) { return ((col ^ (col >> 3)) & 7) << 3; }

// ---------------- weight fragment prep ----------------
__global__ __launch_bounds__(256) void wprep_kernel(const float* __restrict__ convw)
{
    int idx = blockIdx.x * 256 + threadIdx.x;        // [layer][tap][chunk][cogrp][lane]
    if (idx >= NLAYERS * 9 * 4 * 8 * 64) return;
    int lane = idx & 63;
    int cogrp = (idx >> 6) & 7;
    int chunk = (idx >> 9) & 3;
    int t = idx >> 11;
    int layer = t / 9, tap = t - layer * 9;
    int co = cogrp * 16 + (lane & 15);
    int ci0 = chunk * 32 + (lane >> 4) * 8;
    short8 v;
#pragma unroll
    for (int j = 0; j < 8; ++j)
        v[j] = f2b(convw[(((size_t)layer * CCH + co) * CCH + ci0 + j) * 9 + tap]);
    *reinterpret_cast<short8*>(&g_wpack[(size_t)idx * 8]) = v;
}

__global__ void rgbprep_kernel(const float* __restrict__ rgbw)
{
    int idx = blockIdx.x * 256 + threadIdx.x;        // [tap][chunk][lane]
    if (idx >= 9 * 4 * 64) return;
    int lane = idx & 63;
    int chunk = (idx >> 6) & 3;
    int tap = idx >> 8;
    int co = lane & 15;
    int ci0 = chunk * 32 + (lane >> 4) * 8;
    short8 v;
#pragma unroll
    for (int j = 0; j < 8; ++j)
        v[j] = (co < 3) ? f2b(rgbw[((size_t)(co * CCH) + ci0 + j) * 9 + tap]) : (short)0;
    *reinterpret_cast<short8*>(&g_rgbpack[(size_t)idx * 8]) = v;
}

// ---------------- Mapping FC (pixelnorm fused into layer 0; 8-deep ILP) ----------------
__global__ __launch_bounds__(256) void map_fc_kernel(
    int srcSel, int useZ, const float* __restrict__ z,
    const float* __restrict__ W, const float* __restrict__ bias)
{
    float* wout = g_w[srcSel ^ 1];
    int b = blockIdx.y;
    int jb = blockIdx.x * 64;
    int tid = threadIdx.x;
    int jl = tid & 63, kp = tid >> 6;
    __shared__ float xin[D];
    __shared__ float part[4][64];
    __shared__ float wred[4];
    if (useZ) {
        xin[tid] = z[b * D + tid];
        xin[tid + 256] = z[b * D + tid + 256];
    } else {
        const float* win = g_w[srcSel];
        xin[tid] = win[b * D + tid];
        xin[tid + 256] = win[b * D + tid + 256];
    }
    __syncthreads();
    if (useZ) {
        float p = xin[tid] * xin[tid] + xin[tid + 256] * xin[tid + 256];
#pragma unroll
        for (int off = 32; off > 0; off >>= 1) p += __shfl_down(p, off, 64);
        if ((tid & 63) == 0) wred[tid >> 6] = p;
        __syncthreads();
        float ss = wred[0] + wred[1] + wred[2] + wred[3];
        float r = rsqrtf(ss * (1.f / 512.f) + 1e-8f);
        xin[tid] *= r; xin[tid + 256] *= r;
        __syncthreads();
    }
    const float* Wp = W + jb + jl;
    const int k0 = kp * 128;
    float a0 = 0.f, a1 = 0.f, a2 = 0.f, a3 = 0.f, a4 = 0.f, a5 = 0.f, a6 = 0.f, a7 = 0.f;
    for (int k = k0; k < k0 + 128; k += 8) {
        a0 += xin[k + 0] * Wp[(size_t)(k + 0) * D];
        a1 += xin[k + 1] * Wp[(size_t)(k + 1) * D];
        a2 += xin[k + 2] * Wp[(size_t)(k + 2) * D];
        a3 += xin[k + 3] * Wp[(size_t)(k + 3) * D];
        a4 += xin[k + 4] * Wp[(size_t)(k + 4) * D];
        a5 += xin[k + 5] * Wp[(size_t)(k + 5) * D];
        a6 += xin[k + 6] * Wp[(size_t)(k + 6) * D];
        a7 += xin[k + 7] * Wp[(size_t)(k + 7) * D];
    }
    part[kp][jl] = ((a0 + a1) + (a2 + a3)) + ((a4 + a5) + (a6 + a7));
    __syncthreads();
    if (tid < 64) {
        float s = part[0][tid] + part[1][tid] + part[2][tid] + part[3][tid] + bias[jb + tid];
        wout[b * D + jb + tid] = leaky(s);
    }
}

// ---------------- style + rstd for ALL layers, one dispatch ----------------
// grid (8 layers, BS); block 256.
__global__ __launch_bounds__(256) void style_rstd_kernel(
    const float* __restrict__ Aw, const float* __restrict__ Ab,
    const float* __restrict__ convw)
{
    int l = blockIdx.x + 1;        // layers 1..8
    int b = blockIdx.y;
    int tid = threadIdx.x;
    __shared__ float ws_[D];
    __shared__ float part[2][CCH];
    __shared__ float st[CCH];
    ws_[tid] = g_w[0][b * D + tid];
    ws_[tid + 256] = g_w[0][b * D + tid + 256];
    __syncthreads();
    {
        int c = tid & 127, kh = tid >> 7;
        const float* Ap = Aw + (size_t)l * D * CCH + c;
        const int k0 = kh * 256;
        float a0 = 0.f, a1 = 0.f, a2 = 0.f, a3 = 0.f, a4 = 0.f, a5 = 0.f, a6 = 0.f, a7 = 0.f;
        for (int k = k0; k < k0 + 256; k += 8) {
            a0 += ws_[k + 0] * Ap[(size_t)(k + 0) * CCH];
            a1 += ws_[k + 1] * Ap[(size_t)(k + 1) * CCH];
            a2 += ws_[k + 2] * Ap[(size_t)(k + 2) * CCH];
            a3 += ws_[k + 3] * Ap[(size_t)(k + 3) * CCH];
            a4 += ws_[k + 4] * Ap[(size_t)(k + 4) * CCH];
            a5 += ws_[k + 5] * Ap[(size_t)(k + 5) * CCH];
            a6 += ws_[k + 6] * Ap[(size_t)(k + 6) * CCH];
            a7 += ws_[k + 7] * Ap[(size_t)(k + 7) * CCH];
        }
        part[kh][c] = ((a0 + a1) + (a2 + a3)) + ((a4 + a5) + (a6 + a7));
    }
    __syncthreads();
    if (tid < CCH) {
        float s = part[0][tid] + part[1][tid] + Ab[l * CCH + tid];
        st[tid] = s;
        g_style_all[((size_t)l * BS + b) * CCH + tid] = s;
    }
    __syncthreads();
    int colid = tid >> 4, kpart = tid & 15;
    for (int co8 = 0; co8 < 8; ++co8) {
        int cout = co8 * 16 + colid;
        const float* wp = convw + ((size_t)(l * CCH + cout) * CCH + kpart * 8) * 9;
        float wf[72];
#pragma unroll
        for (int q = 0; q < 18; ++q) {
            float4 t = *reinterpret_cast<const float4*>(wp + q * 4);
            wf[q * 4 + 0] = t.x; wf[q * 4 + 1] = t.y; wf[q * 4 + 2] = t.z; wf[q * 4 + 3] = t.w;
        }
        float s = 0.f;
#pragma unroll
        for (int ci = 0; ci < 8; ++ci) {
            float sv = st[kpart * 8 + ci];
#pragma unroll
            for (int k = 0; k < 9; ++k) { float m = wf[ci * 9 + k] * sv; s += m * m; }
        }
#pragma unroll
        for (int off = 8; off > 0; off >>= 1) s += __shfl_down(s, off, 16);
        if (kpart == 0) g_rstd_all[((size_t)l * BS + b) * CCH + cout] = rsqrtf(s + 1e-8f);
    }
}

// ---------------- layer 0: x==0 -> out = leaky(noise*Bw+Bb) * style[1], 4x4 NHWC bf16 ----------------
__global__ void layer0_kernel(const float* __restrict__ noise,
                              const float* __restrict__ Bw, const float* __restrict__ Bb)
{
    int idx = blockIdx.x * 256 + threadIdx.x;
    if (idx >= BS * 16 * CCH) return;
    int c = idx & 127;
    int pix = (idx >> 7) & 15;
    int b = idx >> 11;
    float v = leaky(noise[b * 4096 + pix] * Bw[c] + Bb[c]);
    v *= g_style_all[((size_t)1 * BS + b) * CCH + c];
    g_bufA[((size_t)b * 16 + pix) * CCH + c] = f2b(v);
}

// ---------------- bilinear 2x upsample, bf16 NHWC, vectorized over ci ----------------
__global__ void upsample_kernel(int srcSel, int LWin)
{
    const short* in = srcSel ? g_bufB : g_bufA;
    short* out = srcSel ? g_bufA : g_bufB;
    const int Win = 1 << LWin, Wo = Win * 2;
    const int total = BS * Wo * Wo * 16;
    int idx = blockIdx.x * 256 + threadIdx.x;
    if (idx >= total) return;
    int ck = idx & 15;
    int x = (idx >> 4) & (Wo - 1);
    int y = (idx >> (4 + LWin + 1)) & (Wo - 1);
    int b = idx >> (4 + 2 * (LWin + 1));
    int my = y >> 1, mx = x >> 1;
    int y0, y1, x0, x1;
    float wy0, wy1, wx0, wx1;
    if ((y & 1) == 0) { y0 = my - 1; y1 = my; wy0 = 0.25f; wy1 = 0.75f; if (y0 < 0) { y0 = 0; wy0 = 0.f; wy1 = 1.f; } }
    else              { y0 = my; y1 = my + 1; wy0 = 0.75f; wy1 = 0.25f; if (y1 >= Win) { y1 = Win - 1; wy0 = 1.f; wy1 = 0.f; } }
    if ((x & 1) == 0) { x0 = mx - 1; x1 = mx; wx0 = 0.25f; wx1 = 0.75f; if (x0 < 0) { x0 = 0; wx0 = 0.f; wx1 = 1.f; } }
    else              { x0 = mx; x1 = mx + 1; wx0 = 0.75f; wx1 = 0.25f; if (x1 >= Win) { x1 = Win - 1; wx0 = 1.f; wx1 = 0.f; } }
    const short* base = in + (size_t)b * Win * Win * CCH + ck * 8;
    short8 a00 = *reinterpret_cast<const short8*>(&base[(size_t)(y0 * Win + x0) * CCH]);
    short8 a01 = *reinterpret_cast<const short8*>(&base[(size_t)(y0 * Win + x1) * CCH]);
    short8 a10 = *reinterpret_cast<const short8*>(&base[(size_t)(y1 * Win + x0) * CCH]);
    short8 a11 = *reinterpret_cast<const short8*>(&base[(size_t)(y1 * Win + x1) * CCH]);
    short8 o;
#pragma unroll
    for (int j = 0; j < 8; ++j) {
        float v = wy0 * (wx0 * b2f(a00[j]) + wx1 * b2f(a01[j]))
                + wy1 * (wx0 * b2f(a10[j]) + wx1 * b2f(a11[j]));
        o[j] = f2b(v);
    }
    *reinterpret_cast<short8*>(&out[((size_t)b * Wo * Wo + y * Wo + x) * CCH + ck * 8]) = o;
}

// ---------------- MFMA modulated conv (NHWC bf16 in/out) ----------------
// Block: 64 px (full-width row band) x ALL 128 co; 4 waves; wave owns 2 co-frags.
// LDS xs: [(rr*SW+col)*128 + ci] ^ swz(col), pure b128 copy from NHWC source.
// Epilogue folds style of layerNext (0 = none).
template<int LW>
__global__ __launch_bounds__(256) void conv_mfma_kernel(
    int srcSel, int layer, int layerNext,
    const float* __restrict__ noise,
    const float* __restrict__ Bw, const float* __restrict__ Bb)
{
    constexpr int W = 1 << LW;
    constexpr int R = 64 >> LW;
    constexpr int SW = W + 2;
    constexpr int ROWS = R + 2;
    constexpr int NS = W * W;

    const short* xin = srcSel ? g_bufB : g_bufA;
    short* xout = srcSel ? g_bufA : g_bufB;

    const int b = blockIdx.y;
    const int pixBase = blockIdx.x * 64;
    const int rowBase = pixBase >> LW;
    const int tid = threadIdx.x;
    const int lane = tid & 63;
    const int wave = tid >> 6;

    __shared__ short xs[ROWS * SW * CCH];
    __shared__ float style_s[CCH];

    if (tid < CCH)
        style_s[tid] = layerNext ? g_style_all[((size_t)layerNext * BS + b) * CCH + tid] : 1.f;

    // ---- stage x: pure swizzled b128 copy (source is pre-modulated bf16 NHWC) ----
    {
        const short* src = xin + (size_t)b * NS * CCH;
        constexpr int UN = ROWS * SW * 16;
        for (int u = tid; u < UN; u += 256) {
            int ck = u & 15;
            int rem = u >> 4;
            int col = rem % SW;
            int rr = rem / SW;
            int gy = rowBase + rr - 1, gx = col - 1;
            short8 v = {0, 0, 0, 0, 0, 0, 0, 0};
            if (gy >= 0 && gy < W && gx >= 0 && gx < W)
                v = *reinterpret_cast<const short8*>(&src[((size_t)gy * W + gx) * CCH + ck * 8]);
            *reinterpret_cast<short8*>(&xs[(((rr * SW + col) * CCH) + ck * 8) ^ swz(col)]) = v;
        }
    }
    __syncthreads();

    int rL[4], cL[4];
#pragma unroll
    for (int pf = 0; pf < 4; ++pf) {
        int pl = pf * 16 + (lane & 15);
        cL[pf] = pl & (W - 1);
        rL[pf] = pl >> LW;
    }
    const int grpoff = (lane >> 4) * 8;

    f32x4 acc[2][4] = {};
    const short* wl0 = g_wpack + ((size_t)layer * 9 * 4 * 8 * 64
                                  + (size_t)(wave * 2) * 64 + lane) * 8;
    const short* wl1 = wl0 + 64 * 8;

    short8 wc0 = *reinterpret_cast<const short8*>(wl0);
    short8 wc1 = *reinterpret_cast<const short8*>(wl1);
#pragma unroll
    for (int k = 0; k < 36; ++k) {
        short8 wn0 = wc0, wn1 = wc1;
        if (k + 1 < 36) {
            wn0 = *reinterpret_cast<const short8*>(wl0 + (size_t)(k + 1) * 4096);
            wn1 = *reinterpret_cast<const short8*>(wl1 + (size_t)(k + 1) * 4096);
        }
        const int tap = k >> 2, ch = k & 3;
        const int ky = tap / 3, kx = tap - ky * 3;
#pragma unroll
        for (int pf = 0; pf < 4; ++pf) {
            int col = cL[pf] + kx;
            int idx = (((rL[pf] + ky) * SW + col) * CCH + (ch << 5) + grpoff) ^ swz(col);
            short8 xf = *reinterpret_cast<const short8*>(&xs[idx]);
            acc[0][pf] = __builtin_amdgcn_mfma_f32_16x16x32_bf16(wc0, xf, acc[0][pf], 0, 0, 0);
            acc[1][pf] = __builtin_amdgcn_mfma_f32_16x16x32_bf16(wc1, xf, acc[1][pf], 0, 0, 0);
        }
        wc0 = wn0; wc1 = wn1;
    }

    // ---- epilogue: demod + noise + leaky, fold next style, bf16 NHWC short4 stores ----
    float nz[4];
#pragma unroll
    for (int pf = 0; pf < 4; ++pf)
        nz[pf] = noise[b * 4096 + pixBase + pf * 16 + (lane & 15)];
#pragma unroll
    for (int cf = 0; cf < 2; ++cf) {
        const int coB = (wave * 2 + cf) * 16 + (lane >> 4) * 4;
        float rs[4], bw[4], bb[4], sn[4];
#pragma unroll
        for (int r = 0; r < 4; ++r) {
            rs[r] = g_rstd_all[((size_t)layer * BS + b) * CCH + coB + r];
            bw[r] = Bw[coB + r];
            bb[r] = Bb[coB + r];
            sn[r] = style_s[coB + r];
        }
#pragma unroll
        for (int pf = 0; pf < 4; ++pf) {
            int px = pixBase + pf * 16 + (lane & 15);
            short4v o;
#pragma unroll
            for (int r = 0; r < 4; ++r) {
                float v = leaky(acc[cf][pf][r] * rs[r] + nz[pf] * bw[r] + bb[r]) * sn[r];
                o[r] = f2b(v);
            }
            *reinterpret_cast<short4v*>(&xout[((size_t)b * NS + px) * CCH + coB]) = o;
        }
    }
}

// ---------------- MFMA toRGB (W=64; 3 real rows in 16-row M tile; waves split K) ----------------
__global__ __launch_bounds__(256) void rgb_mfma_kernel(
    int srcSel, const float* __restrict__ rgbb, float* __restrict__ out)
{
    constexpr int W = 64, SW = 66, ROWS = 3, NS = 4096;
    const short* xin = srcSel ? g_bufB : g_bufA;

    const int b = blockIdx.y;
    const int pixBase = blockIdx.x * 64;
    const int rowBase = pixBase >> 6;
    const int tid = threadIdx.x;
    const int lane = tid & 63;
    const int wave = tid >> 6;     // K-chunk

    __shared__ short xs[ROWS * SW * CCH];

    {
        const short* src = xin + (size_t)b * NS * CCH;
        constexpr int UN = ROWS * SW * 16;
        for (int u = tid; u < UN; u += 256) {
            int ck = u & 15;
            int rem = u >> 4;
            int col = rem % SW;
            int rr = rem / SW;
            int gy = rowBase + rr - 1, gx = col - 1;
            short8 v = {0, 0, 0, 0, 0, 0, 0, 0};
            if (gy >= 0 && gy < W && gx >= 0 && gx < W)
                v = *reinterpret_cast<const short8*>(&src[((size_t)gy * W + gx) * CCH + ck * 8]);
            *reinterpret_cast<short8*>(&xs[(((rr * SW + col) * CCH) + ck * 8) ^ swz(col)]) = v;
        }
    }
    __syncthreads();

    const int grpoff = (lane >> 4) * 8;
    const int cl = lane & 15;
    f32x4 acc[4] = {};
#pragma unroll
    for (int tap = 0; tap < 9; ++tap) {
        const int ky = tap / 3, kx = tap - ky * 3;
        short8 wf = *reinterpret_cast<const short8*>(
            &g_rgbpack[((size_t)(tap * 4 + wave) * 64 + lane) * 8]);
#pragma unroll
        for (int pf = 0; pf < 4; ++pf) {
            int col = cl + pf * 16 + kx;
            int idx = ((ky * SW + col) * CCH + (wave << 5) + grpoff) ^ swz(col);
            short8 xf = *reinterpret_cast<const short8*>(&xs[idx]);
            acc[pf] = __builtin_amdgcn_mfma_f32_16x16x32_bf16(wf, xf, acc[pf], 0, 0, 0);
        }
    }
    __syncthreads();
    float* red = reinterpret_cast<float*>(xs);   // reuse LDS for K-reduction
    if (wave > 0) {
#pragma unroll
        for (int pf = 0; pf < 4; ++pf)
#pragma unroll
            for (int r = 0; r < 4; ++r)
                red[(((wave - 1) * 4 + pf) * 64 + lane) * 4 + r] = acc[pf][r];
    }
    __syncthreads();
    if (wave == 0 && (lane >> 4) == 0) {
#pragma unroll
        for (int pf = 0; pf < 4; ++pf) {
            int px = pixBase + pf * 16 + cl;
#pragma unroll
            for (int r = 0; r < 3; ++r) {
                float s = acc[pf][r];
#pragma unroll
                for (int wv = 0; wv < 3; ++wv)
                    s += red[((wv * 4 + pf) * 64 + lane) * 4 + r];
                out[(size_t)(b * 3 + r) * NS + px] = s + rgbb[r];
            }
        }
    }
}

// ---------------- launch ----------------
extern "C" void kernel_launch(void* const* d_in, const int* in_sizes, int n_in,
                              void* d_out, int out_size, void* d_ws, size_t ws_size,
                              hipStream_t stream)
{
    const float* latent = (const float*)d_in[0];
    const float* noise  = (const float*)d_in[1];
    const float* map_w  = (const float*)d_in[2];
    const float* map_b  = (const float*)d_in[3];
    const float* A_w    = (const float*)d_in[4];
    const float* A_b    = (const float*)d_in[5];
    const float* B_w    = (const float*)d_in[6];
    const float* B_b    = (const float*)d_in[7];
    const float* conv_w = (const float*)d_in[8];
    const float* rgb_w  = (const float*)d_in[9];
    const float* rgb_b  = (const float*)d_in[10];
    float* out = (float*)d_out;
    (void)d_ws; (void)ws_size;

    wprep_kernel<<<(NLAYERS * 9 * 4 * 8 * 64 + 255) / 256, 256, 0, stream>>>(conv_w);
    rgbprep_kernel<<<(9 * 4 * 64 + 255) / 256, 256, 0, stream>>>(rgb_w);

    // mapping: layer 0 fuses pixelnorm (reads latent); ping-pong ends in g_w[0]
    int wsel = 0;
    for (int i = 0; i < LMAP; ++i) {
        map_fc_kernel<<<dim3(8, BS), 256, 0, stream>>>(
            wsel, i == 0 ? 1 : 0, latent, map_w + (size_t)i * D * D, map_b + i * D);
        wsel ^= 1;
    }

    style_rstd_kernel<<<dim3(8, BS), 256, 0, stream>>>(A_w, A_b, conv_w);

    layer0_kernel<<<(BS * 16 * CCH + 255) / 256, 256, 0, stream>>>(noise, B_w, B_b);

    int cur = 0;   // 0 => data in g_bufA
    int Hc = 4;
    for (int i = 1; i < NLAYERS; ++i) {
        if (i & 1) {
            int lwin = (Hc == 4) ? 2 : (Hc == 8) ? 3 : (Hc == 16) ? 4 : 5;
            int total = BS * (Hc * 2) * (Hc * 2) * 16;
            upsample_kernel<<<(total + 255) / 256, 256, 0, stream>>>(cur, lwin);
            Hc *= 2;
            cur ^= 1;
        }
        int ns = Hc * Hc;
        int lnext = (i < 8) ? (i + 1) : 0;
        dim3 grid(ns / 64, BS);
        const float* nz = noise + (size_t)i * BS * 4096;
        switch (Hc) {
            case 8:  conv_mfma_kernel<3><<<grid, 256, 0, stream>>>(cur, i, lnext, nz, B_w + i * CCH, B_b + i * CCH); break;
            case 16: conv_mfma_kernel<4><<<grid, 256, 0, stream>>>(cur, i, lnext, nz, B_w + i * CCH, B_b + i * CCH); break;
            case 32: conv_mfma_kernel<5><<<grid, 256, 0, stream>>>(cur, i, lnext, nz, B_w + i * CCH, B_b + i * CCH); break;
            case 64: conv_mfma_kernel<6><<<grid, 256, 0, stream>>>(cur, i, lnext, nz, B_w + i * CCH, B_b + i * CCH); break;
        }
        cur ^= 1;
    }

    rgb_mfma_kernel<<<dim3(64, BS), 256, 0, stream>>>(cur, rgb_b, out);
}